// Round 1
// 347.882 us; speedup vs baseline: 1.0395x; 1.0395x over previous
//
#include <hip/hip_runtime.h>

#define NB 8
#define LSEQ 4096
#define INS 256
#define MD 4
#define ORD 256
#define HID 512
#define MSZ 1280
#define FS 4128   // complex stride for spectrum rows (2*FS = 8256 floats)
#define NSPEC 8256

// padded LDS index for FFT kernels: +1 float2 per 8
#define PD(n) ((n) + ((n) >> 3))
#define LDSN 4608

typedef __attribute__((ext_vector_type(8))) short short8;
typedef __attribute__((ext_vector_type(4))) float floatx4;

struct ush4 { unsigned short x, y, z, w; };

__device__ __forceinline__ unsigned short f2bf(float f) {
    unsigned u = __float_as_uint(f);
    u += 0x7FFF + ((u >> 16) & 1);
    return (unsigned short)(u >> 16);
}
__device__ __forceinline__ ush4 pack4(float4 v) {
    ush4 p; p.x = f2bf(v.x); p.y = f2bf(v.y); p.z = f2bf(v.z); p.w = f2bf(v.w); return p;
}
__device__ __forceinline__ float bf2f(unsigned short s) {
    return __uint_as_float(((unsigned)s) << 16);
}

// ---------------- complex helpers ----------------
__device__ __forceinline__ float2 cmul(float2 a, float2 b) {
    return make_float2(fmaf(a.x, b.x, -(a.y * b.y)), fmaf(a.x, b.y, a.y * b.x));
}
__device__ __forceinline__ float2 cadd(float2 a, float2 b) { return make_float2(a.x + b.x, a.y + b.y); }
__device__ __forceinline__ float2 csub(float2 a, float2 b) { return make_float2(a.x - b.x, a.y - b.y); }

template <int DIR>
__device__ __forceinline__ float2 jmul(float2 z) {
    return (DIR < 0) ? make_float2(z.y, -z.x) : make_float2(-z.y, z.x);
}

// In-place Stockham DIF radix-8 stage on padded buffer. 512 threads.
template <int DIR, int N_, int S_>
__device__ __forceinline__ void fft_stage_ip(float2* __restrict__ X, int tid) {
    constexpr int M_ = N_ / 8;
    const int q = tid & (S_ - 1);
    const int p = tid / S_;
    const int rb = q + S_ * p;
    const float2 a0 = X[PD(rb + S_ * 0 * M_)];
    const float2 a1 = X[PD(rb + S_ * 1 * M_)];
    const float2 a2 = X[PD(rb + S_ * 2 * M_)];
    const float2 a3 = X[PD(rb + S_ * 3 * M_)];
    const float2 a4 = X[PD(rb + S_ * 4 * M_)];
    const float2 a5 = X[PD(rb + S_ * 5 * M_)];
    const float2 a6 = X[PD(rb + S_ * 6 * M_)];
    const float2 a7 = X[PD(rb + S_ * 7 * M_)];

    const float2 e0 = cadd(a0, a4), e1 = csub(a0, a4);
    const float2 e2 = cadd(a2, a6), e3 = jmul<DIR>(csub(a2, a6));
    const float2 E0 = cadd(e0, e2), E2 = csub(e0, e2);
    const float2 E1 = cadd(e1, e3), E3 = csub(e1, e3);
    const float2 f0 = cadd(a1, a5), f1 = csub(a1, a5);
    const float2 f2 = cadd(a3, a7), f3 = jmul<DIR>(csub(a3, a7));
    const float2 O0 = cadd(f0, f2), O2 = csub(f0, f2);
    const float2 O1 = cadd(f1, f3), O3 = csub(f1, f3);

    constexpr float C707 = 0.70710678118654752440f;
    const float2 W1 = make_float2(C707, DIR * C707);
    const float2 W3 = make_float2(-C707, DIR * C707);
    const float2 T1 = cmul(O1, W1);
    const float2 T2 = jmul<DIR>(O2);
    const float2 T3 = cmul(O3, W3);

    const float2 b0 = cadd(E0, O0), b4 = csub(E0, O0);
    const float2 b1 = cadd(E1, T1), b5 = csub(E1, T1);
    const float2 b2 = cadd(E2, T2), b6 = csub(E2, T2);
    const float2 b3 = cadd(E3, T3), b7 = csub(E3, T3);

    float sn, cs;
    __sincosf((DIR * 6.2831853071795864769f / (float)N_) * (float)p, &sn, &cs);
    const float2 w1 = make_float2(cs, sn);

    __syncthreads();

    const int wb = q + S_ * 8 * p;
    X[PD(wb + 0 * S_)] = b0;
    float2 w = w1;
    X[PD(wb + 1 * S_)] = cmul(b1, w); w = cmul(w, w1);
    X[PD(wb + 2 * S_)] = cmul(b2, w); w = cmul(w, w1);
    X[PD(wb + 3 * S_)] = cmul(b3, w); w = cmul(w, w1);
    X[PD(wb + 4 * S_)] = cmul(b4, w); w = cmul(w, w1);
    X[PD(wb + 5 * S_)] = cmul(b5, w); w = cmul(w, w1);
    X[PD(wb + 6 * S_)] = cmul(b6, w); w = cmul(w, w1);
    X[PD(wb + 7 * S_)] = cmul(b7, w);
    __syncthreads();
}

template <int DIR>
__device__ __forceinline__ void fft4096_ip(float2* A, int tid) {
    __syncthreads();
    fft_stage_ip<DIR, 4096, 1>(A, tid);
    fft_stage_ip<DIR, 512, 8>(A, tid);
    fft_stage_ip<DIR, 64, 64>(A, tid);
    fft_stage_ip<DIR, 8, 512>(A, tid);
}

// ---------------- K1: u = relu(x @ Wu_w^T + Wu_b) -> u_t[(b*4+d)][t]; also x_bf = bf16(x).
// Blocks >= 8192 do Whw fp32->bf16 prep (merged former wprep_k). ----------------
extern "C" __global__ __launch_bounds__(256) void u_relu_k(
    const float* __restrict__ x, const float* __restrict__ Wuw,
    const float* __restrict__ Wub, float* __restrict__ u_t,
    unsigned short* __restrict__ x_bf,
    const float* __restrict__ Whw, unsigned short* __restrict__ Whw_bf) {
    const int blk = blockIdx.x;
    if (blk >= 8192) {
        const int idx = (blk - 8192) * 256 + threadIdx.x;  // 640 blocks: 163840 float4s
        const float4 v = ((const float4*)Whw)[idx];
        *(ush4*)(&Whw_bf[(size_t)idx * 4]) = pack4(v);
        return;
    }
    const int gid = blk * 256 + threadIdx.x;
    const int row = gid >> 6;
    const int lane = threadIdx.x & 63;
    const float4 xv = ((const float4*)x)[(size_t)row * 64 + lane];
    *(ush4*)(&x_bf[(size_t)row * 256 + lane * 4]) = pack4(xv);
    const float4 w0 = ((const float4*)Wuw)[0 * 64 + lane];
    const float4 w1 = ((const float4*)Wuw)[1 * 64 + lane];
    const float4 w2 = ((const float4*)Wuw)[2 * 64 + lane];
    const float4 w3 = ((const float4*)Wuw)[3 * 64 + lane];
    float a0 = xv.x * w0.x + xv.y * w0.y + xv.z * w0.z + xv.w * w0.w;
    float a1 = xv.x * w1.x + xv.y * w1.y + xv.z * w1.z + xv.w * w1.w;
    float a2 = xv.x * w2.x + xv.y * w2.y + xv.z * w2.z + xv.w * w2.w;
    float a3 = xv.x * w3.x + xv.y * w3.y + xv.z * w3.z + xv.w * w3.w;
#pragma unroll
    for (int off = 1; off < 64; off <<= 1) {
        a0 += __shfl_xor(a0, off);
        a1 += __shfl_xor(a1, off);
        a2 += __shfl_xor(a2, off);
        a3 += __shfl_xor(a3, off);
    }
    if (lane < 4) {
        float v = (lane == 0) ? a0 : (lane == 1) ? a1 : (lane == 2) ? a2 : a3;
        v = fmaxf(v + Wub[lane], 0.0f);
        const int b = row >> 12, t = row & 4095;
        u_t[((size_t)(b * 4 + lane)) * LSEQ + t] = v;
    }
}

// ---------------- K2: fused rfft. blocks 0..31: u rows -> fftU fp32. blocks 32..287: H rows -> fftHB bf16 row-major ----------------
extern "C" __global__ __launch_bounds__(512) void rfft_all_k(
    const float* __restrict__ ut, const float* __restrict__ H,
    float2* __restrict__ fftU, unsigned short* __restrict__ fftHB) {
    __shared__ float2 A[LDSN];
    const int blk = blockIdx.x;
    const int tid = threadIdx.x;
    const bool is_u = (blk < 32);
    const float* src = is_u ? (ut + (size_t)blk * LSEQ) : (H + (size_t)(blk - 32) * LSEQ);
    const float2* rp = (const float2*)src;
#pragma unroll
    for (int j = 0; j < 8; ++j) {
        const int n = tid + j * 512;
        A[PD(n)] = (n < 2048) ? rp[n] : make_float2(0.f, 0.f);
    }
    fft4096_ip<-1>(A, tid);
    if (is_u) {
        float2* op = fftU + (size_t)blk * FS;
#pragma unroll
        for (int j = 0; j < 9; ++j) {
            const int k = tid + j * 512;
            if (k <= 4096) {
                const float2 Zk = A[PD(k & 4095)];
                const float2 Zm = A[PD((4096 - k) & 4095)];
                const float2 E = make_float2(0.5f * (Zk.x + Zm.x), 0.5f * (Zk.y - Zm.y));
                const float2 D = make_float2(0.5f * (Zk.x - Zm.x), 0.5f * (Zk.y + Zm.y));
                const float2 O = make_float2(D.y, -D.x);
                float sn, cs;
                __sincosf(-7.66990393942820614e-4f * (float)k, &sn, &cs);
                op[k] = cadd(E, cmul(make_float2(cs, sn), O));
            }
        }
    } else {
        const int o = blk - 32;
        unsigned* op = (unsigned*)(fftHB + (size_t)o * NSPEC);  // pair (2k,2k+1) per 4B
#pragma unroll
        for (int j = 0; j < 9; ++j) {
            const int k = tid + j * 512;
            if (k <= 4096) {
                const float2 Zk = A[PD(k & 4095)];
                const float2 Zm = A[PD((4096 - k) & 4095)];
                const float2 E = make_float2(0.5f * (Zk.x + Zm.x), 0.5f * (Zk.y - Zm.y));
                const float2 D = make_float2(0.5f * (Zk.x - Zm.x), 0.5f * (Zk.y + Zm.y));
                const float2 O = make_float2(D.y, -D.x);
                float sn, cs;
                __sincosf(-7.66990393942820614e-4f * (float)k, &sn, &cs);
                const float2 c = cadd(E, cmul(make_float2(cs, sn), O));
                if (2 * k < NSPEC)
                    op[k] = (unsigned)f2bf(c.x) | ((unsigned)f2bf(c.y) << 16);
            }
        }
    }
}

// ---------------- K2b: transpose fftHB [256 o][8256 s] bf16 -> fftHT [8256 s][256 o] bf16 (zero s>=8194) ----------------
extern "C" __global__ __launch_bounds__(256) void ht2_k(
    const unsigned short* __restrict__ fftHB, unsigned short* __restrict__ fftHT) {
    __shared__ unsigned short T[64 * 68];
    const int tid = threadIdx.x;
    const int s0 = blockIdx.x * 64;  // 129 blocks
    const int o0 = blockIdx.y * 64;  // 4 blocks
    const int r = tid >> 4, c4 = (tid & 15) * 4;
#pragma unroll
    for (int i = 0; i < 4; ++i) {
        const int o = r + 16 * i;
        const ush4 v = *(const ush4*)(fftHB + (size_t)(o0 + o) * NSPEC + s0 + c4);
        *(ush4*)(&T[o * 68 + c4]) = v;
    }
    __syncthreads();
#pragma unroll
    for (int i = 0; i < 4; ++i) {
        const int sl = r + 16 * i;
        const int s = s0 + sl;
        ush4 p;
        if (s < 8194) {
            p.x = T[(c4 + 0) * 68 + sl];
            p.y = T[(c4 + 1) * 68 + sl];
            p.z = T[(c4 + 2) * 68 + sl];
            p.w = T[(c4 + 3) * 68 + sl];
        } else { p.x = p.y = p.z = p.w = 0; }
        *(ush4*)(&fftHT[(size_t)s * 256 + o0 + c4]) = p;
    }
}

// ---------------- K4: fftG[m=h*4+d][n] = sum_o Whw_bf[h, d*256+o] * fftHT[n][o]  (bf16 MFMA, bf16 out)
// 1-D grid of 1040 blocks, XCD-bijective swizzle: each XCD owns 2 m-panels x all 65 n-tiles. ----------------
extern "C" __global__ __launch_bounds__(256) void g_gemm_k(
    const unsigned short* __restrict__ Whw_bf, const unsigned short* __restrict__ fftHT,
    unsigned short* __restrict__ fftG) {
    __shared__ __align__(16) char smem[36864];
    short* As = (short*)smem;             // [128][72]
    short* Bs = (short*)(smem + 18432);   // [128][72]
    float* Ct = (float*)smem;             // epilogue reuse: [128][68]

    const int tid = threadIdx.x, lane = tid & 63, wave = tid >> 6;
    // swizzle: 1040 blocks = 8 XCDs * 130; XCD x gets s in [x*130, x*130+130) = 2 m-rows * 65 n
    const int wg = blockIdx.x;
    const int s = (wg & 7) * 130 + (wg >> 3);
    const int n0 = (s % 65) * 128;  // 65 tiles, last partial
    const int m0 = (s / 65) * 128;  // 16 tiles over 2048 rows
    floatx4 acc[2][8];
#pragma unroll
    for (int i = 0; i < 2; ++i)
#pragma unroll
        for (int j = 0; j < 8; ++j) acc[i][j] = (floatx4){0.f, 0.f, 0.f, 0.f};

    const int sr = tid >> 4, sc = (tid & 15) * 4;
    for (int kc = 0; kc < 4; ++kc) {
#pragma unroll
        for (int i = 0; i < 8; ++i) {
            const int row = sr + 16 * i;
            const int m = m0 + row;
            const ush4 av = *(const ush4*)(Whw_bf + (size_t)(m >> 2) * MSZ + (m & 3) * 256 + kc * 64 + sc);
            *(ush4*)(&As[row * 72 + sc]) = av;
            const int n = n0 + row;
            ush4 bv;
            if (n < NSPEC) bv = *(const ush4*)(fftHT + (size_t)n * 256 + kc * 64 + sc);
            else { bv.x = bv.y = bv.z = bv.w = 0; }
            *(ush4*)(&Bs[row * 72 + sc]) = bv;
        }
        __syncthreads();
        const int arow = (wave * 32 + (lane & 15)) * 72;
        const int brow = (lane & 15) * 72;
        const int kq = 8 * (lane >> 4);
#pragma unroll
        for (int kk = 0; kk < 2; ++kk) {
            const int ko = kk * 32 + kq;
            const short8 a0 = *(const short8*)(&As[arow + ko]);
            const short8 a1 = *(const short8*)(&As[arow + 16 * 72 + ko]);
#pragma unroll
            for (int nf = 0; nf < 8; ++nf) {
                const short8 bv = *(const short8*)(&Bs[brow + nf * 16 * 72 + ko]);
                acc[0][nf] = __builtin_amdgcn_mfma_f32_16x16x32_bf16(a0, bv, acc[0][nf], 0, 0, 0);
                acc[1][nf] = __builtin_amdgcn_mfma_f32_16x16x32_bf16(a1, bv, acc[1][nf], 0, 0, 0);
            }
        }
        __syncthreads();
    }
    // epilogue: transpose C through LDS, pack bf16, 8B-coalesced stores
    const int wm = wave * 32;
#pragma unroll 1
    for (int half = 0; half < 2; ++half) {
        __syncthreads();
#pragma unroll
        for (int nfl = 0; nfl < 4; ++nfl) {
            const int nf = half * 4 + nfl;
            const int nloc = nfl * 16 + (lane & 15);
#pragma unroll
            for (int mf = 0; mf < 2; ++mf)
#pragma unroll
                for (int r = 0; r < 4; ++r) {
                    const int row = wm + mf * 16 + 4 * (lane >> 4) + r;
                    Ct[row * 68 + nloc] = acc[mf][nf][r];
                }
        }
        __syncthreads();
#pragma unroll
        for (int i = 0; i < 8; ++i) {
            const int idx = tid + i * 256;
            const int row = idx >> 4, f4 = idx & 15;
            const int n = n0 + half * 64 + f4 * 4;
            if (n < NSPEC) {
                const float4 v = *(const float4*)&Ct[row * 68 + f4 * 4];
                *(ush4*)&fftG[(size_t)(m0 + row) * NSPEC + n] = pack4(v);
            }
        }
    }
}

// ---------------- K5: S = sum_d fftU[b,d] * fftG[h,d]; y[b,h,:] = irfft(S)[0:4096] (bf16 out)
// XCD-bijective swizzle: all 8 b of one h land on the same XCD (G row -> L2 hit). ----------------
extern "C" __global__ __launch_bounds__(512) void conv_ifft_k(
    const float2* __restrict__ fftU, const unsigned short* __restrict__ fftG,
    unsigned short* __restrict__ y) {
    __shared__ float2 A[LDSN];
    __shared__ float2 S4096;
    const int wg = blockIdx.x;  // 4096 blocks
    const int h = ((wg & 7) << 6) + (wg >> 6);  // XCD (wg&7) owns h range [x*64, x*64+64)
    const int b = (wg >> 3) & 7;
    const int tid = threadIdx.x;
    const float2* U = fftU + (size_t)b * MD * FS;
    const unsigned short* G = fftG + (size_t)h * MD * NSPEC;
#pragma unroll
    for (int j = 0; j < 9; ++j) {
        const int k = tid + j * 512;
        if (k <= 4096) {
            float2 s = make_float2(0.f, 0.f);
#pragma unroll
            for (int d = 0; d < MD; ++d) {
                const float2 uu = U[d * FS + k];
                const unsigned gv = *(const unsigned*)(G + (size_t)d * NSPEC + 2 * k);
                const float gx = __uint_as_float(gv << 16);
                const float gy = __uint_as_float(gv & 0xFFFF0000u);
                s.x = fmaf(uu.x, gx, fmaf(-uu.y, gy, s.x));
                s.y = fmaf(uu.x, gy, fmaf(uu.y, gx, s.y));
            }
            if (k < 4096) A[PD(k)] = s;
            else S4096 = s;
        }
    }
    __syncthreads();
    float2 Sk[8], Sm[8];
#pragma unroll
    for (int j = 0; j < 8; ++j) {
        const int k = tid + j * 512;
        Sk[j] = A[PD(k)];
        Sm[j] = (k == 0) ? S4096 : A[PD(4096 - k)];
    }
    __syncthreads();
#pragma unroll
    for (int j = 0; j < 8; ++j) {
        const int k = tid + j * 512;
        const float2 E = make_float2(0.5f * (Sk[j].x + Sm[j].x), 0.5f * (Sk[j].y - Sm[j].y));
        const float2 D = make_float2(0.5f * (Sk[j].x - Sm[j].x), 0.5f * (Sk[j].y + Sm[j].y));
        float sn, cs;
        __sincosf(7.66990393942820614e-4f * (float)k, &sn, &cs);
        const float2 O = cmul(D, make_float2(cs, sn));
        A[PD(k)] = make_float2(E.x - O.y, E.y + O.x);
    }
    fft4096_ip<1>(A, tid);
    unsigned short* yp = y + (size_t)(b * HID + h) * LSEQ;
    const float inv = 1.0f / 4096.0f;
#pragma unroll
    for (int j = 0; j < 4; ++j) {
        const int n = tid + j * 512;
        const float2 z = A[PD(n)];
        const unsigned pk = (unsigned)f2bf(z.x * inv) | ((unsigned)f2bf(z.y * inv) << 16);
        *(unsigned*)(yp + 2 * n) = pk;  // x[2n], x[2n+1] as bf16 pair
    }
}

// ---------------- K6: h = relu(x @ Whw_x^T + y^T + bias) via bf16 MFMA; also h_last
// 1-D grid of 1024 blocks; swizzle keeps the 4 h-tiles of one m-tile adjacent on one XCD.
// Plain (write-back) stores — NT 16B/lane stores were the suspected HBM write-amplification. ----------------
extern "C" __global__ __launch_bounds__(256) void out_gemm_k(
    const unsigned short* __restrict__ x_bf, const unsigned short* __restrict__ Whw_bf,
    const float* __restrict__ Whb, const unsigned short* __restrict__ y,
    float* __restrict__ out) {
    __shared__ __align__(16) char smem[36864];
    short* As = (short*)smem;             // [128][72]
    short* Bs = (short*)(smem + 18432);   // [128][72]
    float* Ys = (float*)smem;             // epilogue: [64][132] (aliased, barrier-separated)
    float* Ct = (float*)smem;             // epilogue: [128][68]

    const int tid = threadIdx.x, lane = tid & 63, wave = tid >> 6;
    // swizzle: 1024 blocks = 8 XCDs * 128; within an XCD, s runs m-major with the 4 h-tiles adjacent
    const int wg = blockIdx.x;
    const int s = ((wg & 7) << 7) + (wg >> 3);
    const int m0 = (s >> 2) * 128;   // 256 m-tiles
    const int h0 = (s & 3) * 128;    // 4 h-tiles
    const int b = m0 >> 12;
    const int t0 = m0 & 4095;

    floatx4 acc[2][8];
#pragma unroll
    for (int i = 0; i < 2; ++i)
#pragma unroll
        for (int j = 0; j < 8; ++j) acc[i][j] = (floatx4){0.f, 0.f, 0.f, 0.f};

    const int sr = tid >> 4, sc = (tid & 15) * 4;
    const unsigned short* Axp = x_bf + (size_t)(m0 + sr) * INS + sc;
    const unsigned short* Bxp = Whw_bf + (size_t)(h0 + sr) * MSZ + 1024 + sc;

    for (int kc = 0; kc < 4; ++kc) {
#pragma unroll
        for (int i = 0; i < 8; ++i) {
            const int row = sr + 16 * i;
            *(ush4*)(&As[row * 72 + sc]) = *(const ush4*)(Axp + (size_t)(16 * i) * INS + kc * 64);
            *(ush4*)(&Bs[row * 72 + sc]) = *(const ush4*)(Bxp + (size_t)(16 * i) * MSZ + kc * 64);
        }
        __syncthreads();
        const int arow = (wave * 32 + (lane & 15)) * 72;
        const int brow = (lane & 15) * 72;
        const int kq = 8 * (lane >> 4);
#pragma unroll
        for (int kk = 0; kk < 2; ++kk) {
            const int ko = kk * 32 + kq;
            const short8 a0 = *(const short8*)(&As[arow + ko]);
            const short8 a1 = *(const short8*)(&As[arow + 16 * 72 + ko]);
#pragma unroll
            for (int nf = 0; nf < 8; ++nf) {
                const short8 bv = *(const short8*)(&Bs[brow + nf * 16 * 72 + ko]);
                acc[0][nf] = __builtin_amdgcn_mfma_f32_16x16x32_bf16(a0, bv, acc[0][nf], 0, 0, 0);
                acc[1][nf] = __builtin_amdgcn_mfma_f32_16x16x32_bf16(a1, bv, acc[1][nf], 0, 0, 0);
            }
        }
        __syncthreads();
    }

    // epilogue per 64-h half: stage y^T (bf16->fp32) -> relu(acc+y+bias) in regs
    // -> transpose via LDS -> float4 stores (write-back, line-merged)
    const int wm = wave * 32;
    const int yr = tid >> 5, yc = (tid & 31) * 4;
#pragma unroll 1
    for (int half = 0; half < 2; ++half) {
        __syncthreads();
#pragma unroll
        for (int i = 0; i < 8; ++i) {
            const int hh = yr + 8 * i;
            const ush4 v = *(const ush4*)(y + (size_t)(b * HID + h0 + half * 64 + hh) * LSEQ + t0 + yc);
            Ys[hh * 132 + yc + 0] = bf2f(v.x);
            Ys[hh * 132 + yc + 1] = bf2f(v.y);
            Ys[hh * 132 + yc + 2] = bf2f(v.z);
            Ys[hh * 132 + yc + 3] = bf2f(v.w);
        }
        __syncthreads();
        float v[4][2][4];
#pragma unroll
        for (int nfl = 0; nfl < 4; ++nfl) {
            const int nf = half * 4 + nfl;
            const int hh = nfl * 16 + (lane & 15);
            const float bias = Whb[h0 + half * 64 + hh];
#pragma unroll
            for (int mf = 0; mf < 2; ++mf)
#pragma unroll
                for (int r = 0; r < 4; ++r) {
                    const int row = wm + mf * 16 + 4 * (lane >> 4) + r;
                    v[nfl][mf][r] = fmaxf(acc[mf][nf][r] + Ys[hh * 132 + row] + bias, 0.f);
                }
        }
        __syncthreads();
#pragma unroll
        for (int nfl = 0; nfl < 4; ++nfl) {
            const int nloc = nfl * 16 + (lane & 15);
#pragma unroll
            for (int mf = 0; mf < 2; ++mf)
#pragma unroll
                for (int r = 0; r < 4; ++r) {
                    const int row = wm + mf * 16 + 4 * (lane >> 4) + r;
                    Ct[row * 68 + nloc] = v[nfl][mf][r];
                }
        }
        __syncthreads();
#pragma unroll
        for (int i = 0; i < 8; ++i) {
            const int idx = tid + i * 256;
            const int row = idx >> 4, f4 = idx & 15;
            const floatx4 t = *(const floatx4*)&Ct[row * 68 + f4 * 4];
            *(floatx4*)(out + (size_t)(m0 + row) * HID + h0 + half * 64 + f4 * 4) = t;
            if (((m0 + row) & 4095) == 4095)
                *(floatx4*)(out + (size_t)NB * LSEQ * HID + (size_t)b * HID + h0 + half * 64 + f4 * 4) = t;
        }
    }
}

extern "C" void kernel_launch(void* const* d_in, const int* in_sizes, int n_in,
                              void* d_out, int out_size, void* d_ws, size_t ws_size,
                              hipStream_t stream) {
    const float* x   = (const float*)d_in[0];
    const float* Wuw = (const float*)d_in[1];
    const float* Wub = (const float*)d_in[2];
    const float* Whw = (const float*)d_in[3];
    const float* Whb = (const float*)d_in[4];
    const float* H   = (const float*)d_in[5];
    char* wsb = (char*)d_ws;
    // workspace layout (bytes) — total ~95.5 MB
    unsigned short* fftG   = (unsigned short*)(wsb);             // 2048*8256 bf16   = 33,816,576
    unsigned short* yb     = (unsigned short*)(wsb + 33816576);  // 8*512*4096 bf16  = 33,554,432
    float*          fftU   = (float*)(wsb + 67371008);           // 32*4128*2 fp32   =  1,056,768
    unsigned short* fftHT  = (unsigned short*)(wsb + 68427776);  // 8256*256 bf16    =  4,227,072
    float*          ut     = (float*)(wsb + 72654848);           // 32*4096 fp32     =    524,288
    unsigned short* x_bf   = (unsigned short*)(wsb + 73179136);  // 32768*256 bf16   = 16,777,216
    unsigned short* Whw_bf = (unsigned short*)(wsb + 89956352);  // 512*1280 bf16    =  1,310,720
    unsigned short* fftHB  = (unsigned short*)(wsb + 91267072);  // 256*8256 bf16    =  4,227,072
    float* out = (float*)d_out;

    hipLaunchKernelGGL(u_relu_k, dim3(8832), dim3(256), 0, stream, x, Wuw, Wub, ut, x_bf, Whw, Whw_bf);
    hipLaunchKernelGGL(rfft_all_k, dim3(288), dim3(512), 0, stream, ut, H, (float2*)fftU, fftHB);
    hipLaunchKernelGGL(ht2_k, dim3(129, 4), dim3(256), 0, stream, fftHB, fftHT);
    hipLaunchKernelGGL(g_gemm_k, dim3(1040), dim3(256), 0, stream, Whw_bf, fftHT, fftG);
    hipLaunchKernelGGL(conv_ifft_k, dim3(4096), dim3(512), 0, stream,
                       (const float2*)fftU, fftG, yb);
    hipLaunchKernelGGL(out_gemm_k, dim3(1024), dim3(256), 0, stream, x_bf, Whw_bf, Whb, yb, out);
}

// Round 3
// 339.492 us; speedup vs baseline: 1.0651x; 1.0247x over previous
//
#include <hip/hip_runtime.h>

#define NB 8
#define LSEQ 4096
#define INS 256
#define MD 4
#define ORD 256
#define HID 512
#define MSZ 1280
#define FS 4128   // complex stride for spectrum rows (2*FS = 8256 floats)
#define NSPEC 8256

// padded LDS index for FFT kernels: +1 float2 per 8
#define PD(n) ((n) + ((n) >> 3))
#define LDSN 4608

typedef __attribute__((ext_vector_type(8))) short short8;
typedef __attribute__((ext_vector_type(4))) float floatx4;

struct ush4 { unsigned short x, y, z, w; };

// Twiddle tables live in the code object's device memory — NOT the workspace
// (round-2 container crash was plausibly a workspace overflow; ws layout is
// reverted to the exact round-1 footprint).
__device__ float2 g_tw4096[4096];   // exp(-2*pi*i*j/4096)
__device__ float2 g_tw8192[4098];   // exp(-2*pi*i*k/8192), k<=4097

__device__ __forceinline__ unsigned short f2bf(float f) {
    unsigned u = __float_as_uint(f);
    u += 0x7FFF + ((u >> 16) & 1);
    return (unsigned short)(u >> 16);
}
__device__ __forceinline__ ush4 pack4(float4 v) {
    ush4 p; p.x = f2bf(v.x); p.y = f2bf(v.y); p.z = f2bf(v.z); p.w = f2bf(v.w); return p;
}
__device__ __forceinline__ float bf2f(unsigned short s) {
    return __uint_as_float(((unsigned)s) << 16);
}

// ---------------- complex helpers ----------------
__device__ __forceinline__ float2 cmul(float2 a, float2 b) {
    return make_float2(fmaf(a.x, b.x, -(a.y * b.y)), fmaf(a.x, b.y, a.y * b.x));
}
__device__ __forceinline__ float2 cadd(float2 a, float2 b) { return make_float2(a.x + b.x, a.y + b.y); }
__device__ __forceinline__ float2 csub(float2 a, float2 b) { return make_float2(a.x - b.x, a.y - b.y); }

template <int DIR>
__device__ __forceinline__ float2 jmul(float2 z) {
    return (DIR < 0) ? make_float2(z.y, -z.x) : make_float2(-z.y, z.x);
}

// In-place Stockham DIF radix-8 stage on padded buffer. 512 threads.
// Twiddles from precomputed table TW[j] = exp(-2*pi*i*j/4096); DIR=+1 uses conj.
template <int DIR, int N_, int S_>
__device__ __forceinline__ void fft_stage_ip(float2* __restrict__ X, int tid) {
    constexpr int M_ = N_ / 8;
    constexpr int STEP = 4096 / N_;
    const int q = tid & (S_ - 1);
    const int p = tid / S_;
    const int rb = q + S_ * p;
    const float2 a0 = X[PD(rb + S_ * 0 * M_)];
    const float2 a1 = X[PD(rb + S_ * 1 * M_)];
    const float2 a2 = X[PD(rb + S_ * 2 * M_)];
    const float2 a3 = X[PD(rb + S_ * 3 * M_)];
    const float2 a4 = X[PD(rb + S_ * 4 * M_)];
    const float2 a5 = X[PD(rb + S_ * 5 * M_)];
    const float2 a6 = X[PD(rb + S_ * 6 * M_)];
    const float2 a7 = X[PD(rb + S_ * 7 * M_)];

    // table twiddles (independent loads, issue early; exact w^j, no serial chain)
    const int pw = p * STEP;
    float2 w[7];
#pragma unroll
    for (int j = 1; j <= 7; ++j) {
        float2 t = g_tw4096[pw * j];   // pw*j < 4096 always (p < N_/8)
        if (DIR > 0) t.y = -t.y;
        w[j - 1] = t;
    }

    const float2 e0 = cadd(a0, a4), e1 = csub(a0, a4);
    const float2 e2 = cadd(a2, a6), e3 = jmul<DIR>(csub(a2, a6));
    const float2 E0 = cadd(e0, e2), E2 = csub(e0, e2);
    const float2 E1 = cadd(e1, e3), E3 = csub(e1, e3);
    const float2 f0 = cadd(a1, a5), f1 = csub(a1, a5);
    const float2 f2 = cadd(a3, a7), f3 = jmul<DIR>(csub(a3, a7));
    const float2 O0 = cadd(f0, f2), O2 = csub(f0, f2);
    const float2 O1 = cadd(f1, f3), O3 = csub(f1, f3);

    constexpr float C707 = 0.70710678118654752440f;
    const float2 W1 = make_float2(C707, DIR * C707);
    const float2 W3 = make_float2(-C707, DIR * C707);
    const float2 T1 = cmul(O1, W1);
    const float2 T2 = jmul<DIR>(O2);
    const float2 T3 = cmul(O3, W3);

    const float2 b0 = cadd(E0, O0), b4 = csub(E0, O0);
    const float2 b1 = cadd(E1, T1), b5 = csub(E1, T1);
    const float2 b2 = cadd(E2, T2), b6 = csub(E2, T2);
    const float2 b3 = cadd(E3, T3), b7 = csub(E3, T3);

    __syncthreads();

    const int wb = q + S_ * 8 * p;
    X[PD(wb + 0 * S_)] = b0;
    X[PD(wb + 1 * S_)] = cmul(b1, w[0]);
    X[PD(wb + 2 * S_)] = cmul(b2, w[1]);
    X[PD(wb + 3 * S_)] = cmul(b3, w[2]);
    X[PD(wb + 4 * S_)] = cmul(b4, w[3]);
    X[PD(wb + 5 * S_)] = cmul(b5, w[4]);
    X[PD(wb + 6 * S_)] = cmul(b6, w[5]);
    X[PD(wb + 7 * S_)] = cmul(b7, w[6]);
    __syncthreads();
}

template <int DIR>
__device__ __forceinline__ void fft4096_ip(float2* A, int tid) {
    __syncthreads();
    fft_stage_ip<DIR, 4096, 1>(A, tid);
    fft_stage_ip<DIR, 512, 8>(A, tid);
    fft_stage_ip<DIR, 64, 64>(A, tid);
    fft_stage_ip<DIR, 8, 512>(A, tid);
}

// ---------------- K1: u = relu(x @ Wu_w^T + Wu_b) -> u_t[(b*4+d)][t]; also x_bf = bf16(x).
// Blocks 8192..8831: Whw fp32->bf16 prep. Blocks 8832..8864: twiddle table fill. ----------------
extern "C" __global__ __launch_bounds__(256) void u_relu_k(
    const float* __restrict__ x, const float* __restrict__ Wuw,
    const float* __restrict__ Wub, float* __restrict__ u_t,
    unsigned short* __restrict__ x_bf,
    const float* __restrict__ Whw, unsigned short* __restrict__ Whw_bf) {
    const int blk = blockIdx.x;
    if (blk >= 8832) {
        // one-time twiddle tables (accurate sincosf)
        if (blk < 8848) {
            const int i = (blk - 8832) * 256 + threadIdx.x;  // exactly 4096
            float sn, cs;
            sincosf(-1.53398078788564403e-3f * (float)i, &sn, &cs);  // -2pi/4096
            g_tw4096[i] = make_float2(cs, sn);
        } else {
            const int i = (blk - 8848) * 256 + threadIdx.x;
            if (i <= 4097) {
                float sn, cs;
                sincosf(-7.66990393942820614e-4f * (float)i, &sn, &cs);  // -2pi/8192
                g_tw8192[i] = make_float2(cs, sn);
            }
        }
        return;
    }
    if (blk >= 8192) {
        const int idx = (blk - 8192) * 256 + threadIdx.x;  // 640 blocks: 163840 float4s
        const float4 v = ((const float4*)Whw)[idx];
        *(ush4*)(&Whw_bf[(size_t)idx * 4]) = pack4(v);
        return;
    }
    const int gid = blk * 256 + threadIdx.x;
    const int row = gid >> 6;
    const int lane = threadIdx.x & 63;
    const float4 xv = ((const float4*)x)[(size_t)row * 64 + lane];
    *(ush4*)(&x_bf[(size_t)row * 256 + lane * 4]) = pack4(xv);
    const float4 w0 = ((const float4*)Wuw)[0 * 64 + lane];
    const float4 w1 = ((const float4*)Wuw)[1 * 64 + lane];
    const float4 w2 = ((const float4*)Wuw)[2 * 64 + lane];
    const float4 w3 = ((const float4*)Wuw)[3 * 64 + lane];
    float a0 = xv.x * w0.x + xv.y * w0.y + xv.z * w0.z + xv.w * w0.w;
    float a1 = xv.x * w1.x + xv.y * w1.y + xv.z * w1.z + xv.w * w1.w;
    float a2 = xv.x * w2.x + xv.y * w2.y + xv.z * w2.z + xv.w * w2.w;
    float a3 = xv.x * w3.x + xv.y * w3.y + xv.z * w3.z + xv.w * w3.w;
#pragma unroll
    for (int off = 1; off < 64; off <<= 1) {
        a0 += __shfl_xor(a0, off);
        a1 += __shfl_xor(a1, off);
        a2 += __shfl_xor(a2, off);
        a3 += __shfl_xor(a3, off);
    }
    if (lane < 4) {
        float v = (lane == 0) ? a0 : (lane == 1) ? a1 : (lane == 2) ? a2 : a3;
        v = fmaxf(v + Wub[lane], 0.0f);
        const int b = row >> 12, t = row & 4095;
        u_t[((size_t)(b * 4 + lane)) * LSEQ + t] = v;
    }
}

// ---------------- K2: fused rfft. blocks 0..31: u rows -> fftU fp32. blocks 32..287: H rows -> fftHB bf16 row-major ----------------
extern "C" __global__ __launch_bounds__(512) void rfft_all_k(
    const float* __restrict__ ut, const float* __restrict__ H,
    float2* __restrict__ fftU, unsigned short* __restrict__ fftHB) {
    __shared__ float2 A[LDSN];
    const int blk = blockIdx.x;
    const int tid = threadIdx.x;
    const bool is_u = (blk < 32);
    const float* src = is_u ? (ut + (size_t)blk * LSEQ) : (H + (size_t)(blk - 32) * LSEQ);
    const float2* rp = (const float2*)src;
#pragma unroll
    for (int j = 0; j < 8; ++j) {
        const int n = tid + j * 512;
        A[PD(n)] = (n < 2048) ? rp[n] : make_float2(0.f, 0.f);
    }
    fft4096_ip<-1>(A, tid);
    if (is_u) {
        float2* op = fftU + (size_t)blk * FS;
#pragma unroll
        for (int j = 0; j < 9; ++j) {
            const int k = tid + j * 512;
            if (k <= 4096) {
                const float2 Zk = A[PD(k & 4095)];
                const float2 Zm = A[PD((4096 - k) & 4095)];
                const float2 E = make_float2(0.5f * (Zk.x + Zm.x), 0.5f * (Zk.y - Zm.y));
                const float2 D = make_float2(0.5f * (Zk.x - Zm.x), 0.5f * (Zk.y + Zm.y));
                const float2 O = make_float2(D.y, -D.x);
                const float2 t = g_tw8192[k];  // exp(-2*pi*i*k/8192)
                op[k] = cadd(E, cmul(t, O));
            }
        }
    } else {
        const int o = blk - 32;
        unsigned* op = (unsigned*)(fftHB + (size_t)o * NSPEC);  // pair (2k,2k+1) per 4B
#pragma unroll
        for (int j = 0; j < 9; ++j) {
            const int k = tid + j * 512;
            if (k <= 4096) {
                const float2 Zk = A[PD(k & 4095)];
                const float2 Zm = A[PD((4096 - k) & 4095)];
                const float2 E = make_float2(0.5f * (Zk.x + Zm.x), 0.5f * (Zk.y - Zm.y));
                const float2 D = make_float2(0.5f * (Zk.x - Zm.x), 0.5f * (Zk.y + Zm.y));
                const float2 O = make_float2(D.y, -D.x);
                const float2 t = g_tw8192[k];
                const float2 c = cadd(E, cmul(t, O));
                if (2 * k < NSPEC)
                    op[k] = (unsigned)f2bf(c.x) | ((unsigned)f2bf(c.y) << 16);
            }
        }
    }
}

// ---------------- K2b: transpose fftHB [256 o][8256 s] bf16 -> fftHT [8256 s][256 o] bf16 (zero s>=8194) ----------------
extern "C" __global__ __launch_bounds__(256) void ht2_k(
    const unsigned short* __restrict__ fftHB, unsigned short* __restrict__ fftHT) {
    __shared__ unsigned short T[64 * 68];
    const int tid = threadIdx.x;
    const int s0 = blockIdx.x * 64;  // 129 blocks
    const int o0 = blockIdx.y * 64;  // 4 blocks
    const int r = tid >> 4, c4 = (tid & 15) * 4;
#pragma unroll
    for (int i = 0; i < 4; ++i) {
        const int o = r + 16 * i;
        const ush4 v = *(const ush4*)(fftHB + (size_t)(o0 + o) * NSPEC + s0 + c4);
        *(ush4*)(&T[o * 68 + c4]) = v;
    }
    __syncthreads();
#pragma unroll
    for (int i = 0; i < 4; ++i) {
        const int sl = r + 16 * i;
        const int s = s0 + sl;
        ush4 p;
        if (s < 8194) {
            p.x = T[(c4 + 0) * 68 + sl];
            p.y = T[(c4 + 1) * 68 + sl];
            p.z = T[(c4 + 2) * 68 + sl];
            p.w = T[(c4 + 3) * 68 + sl];
        } else { p.x = p.y = p.z = p.w = 0; }
        *(ush4*)(&fftHT[(size_t)s * 256 + o0 + c4]) = p;
    }
}

// ---------------- K4: fftG[m=h*4+d][n] = sum_o Whw_bf[h, d*256+o] * fftHT[n][o]  (bf16 MFMA, bf16 out)
// XCD-bijective swizzle; reg-staged prefetch: tile kc+1 loads issue under tile kc's MFMA. ----------------
extern "C" __global__ __launch_bounds__(256) void g_gemm_k(
    const unsigned short* __restrict__ Whw_bf, const unsigned short* __restrict__ fftHT,
    unsigned short* __restrict__ fftG) {
    __shared__ __align__(16) char smem[36864];
    short* As = (short*)smem;             // [128][72]
    short* Bs = (short*)(smem + 18432);   // [128][72]
    float* Ct = (float*)smem;             // epilogue reuse: [128][68]

    const int tid = threadIdx.x, lane = tid & 63, wave = tid >> 6;
    // swizzle: 1040 blocks = 8 XCDs * 130; XCD x gets s in [x*130, x*130+130) = 2 m-rows * 65 n
    const int wg = blockIdx.x;
    const int s = (wg & 7) * 130 + (wg >> 3);
    const int n0 = (s % 65) * 128;  // 65 tiles, last partial
    const int m0 = (s / 65) * 128;  // 16 tiles over 2048 rows
    floatx4 acc[2][8];
#pragma unroll
    for (int i = 0; i < 2; ++i)
#pragma unroll
        for (int j = 0; j < 8; ++j) acc[i][j] = (floatx4){0.f, 0.f, 0.f, 0.f};

    // 16-B/lane staging: 32 rows per pass, 4 passes cover 128 rows x 64 k
    const int lr = tid >> 3;           // 0..31
    const int lc = (tid & 7) * 8;      // bf16 col: 0..56
    short8 ra[4], rb[4];

#define GL_A(kc, i) (*(const short8*)(Whw_bf + (size_t)((m0 + lr + 32 * (i)) >> 2) * MSZ + ((m0 + lr + 32 * (i)) & 3) * 256 + (kc) * 64 + lc))
#pragma unroll
    for (int i = 0; i < 4; ++i) {
        ra[i] = GL_A(0, i);
        const int n = n0 + lr + 32 * i;
        rb[i] = (n < NSPEC) ? *(const short8*)(fftHT + (size_t)n * 256 + lc)
                            : (short8){0, 0, 0, 0, 0, 0, 0, 0};
    }

    for (int kc = 0; kc < 4; ++kc) {
#pragma unroll
        for (int i = 0; i < 4; ++i) {
            *(short8*)(&As[(lr + 32 * i) * 72 + lc]) = ra[i];
            *(short8*)(&Bs[(lr + 32 * i) * 72 + lc]) = rb[i];
        }
        __syncthreads();
        if (kc < 3) {
#pragma unroll
            for (int i = 0; i < 4; ++i) {
                ra[i] = GL_A(kc + 1, i);
                const int n = n0 + lr + 32 * i;
                rb[i] = (n < NSPEC) ? *(const short8*)(fftHT + (size_t)n * 256 + (kc + 1) * 64 + lc)
                                    : (short8){0, 0, 0, 0, 0, 0, 0, 0};
            }
        }
        const int arow = (wave * 32 + (lane & 15)) * 72;
        const int brow = (lane & 15) * 72;
        const int kq = 8 * (lane >> 4);
#pragma unroll
        for (int kk = 0; kk < 2; ++kk) {
            const int ko = kk * 32 + kq;
            const short8 a0 = *(const short8*)(&As[arow + ko]);
            const short8 a1 = *(const short8*)(&As[arow + 16 * 72 + ko]);
#pragma unroll
            for (int nf = 0; nf < 8; ++nf) {
                const short8 bv = *(const short8*)(&Bs[brow + nf * 16 * 72 + ko]);
                acc[0][nf] = __builtin_amdgcn_mfma_f32_16x16x32_bf16(a0, bv, acc[0][nf], 0, 0, 0);
                acc[1][nf] = __builtin_amdgcn_mfma_f32_16x16x32_bf16(a1, bv, acc[1][nf], 0, 0, 0);
            }
        }
        __syncthreads();
    }
#undef GL_A
    // epilogue: transpose C through LDS, pack bf16, 8B-coalesced stores
    const int wm = wave * 32;
#pragma unroll 1
    for (int half = 0; half < 2; ++half) {
        __syncthreads();
#pragma unroll
        for (int nfl = 0; nfl < 4; ++nfl) {
            const int nf = half * 4 + nfl;
            const int nloc = nfl * 16 + (lane & 15);
#pragma unroll
            for (int mf = 0; mf < 2; ++mf)
#pragma unroll
                for (int r = 0; r < 4; ++r) {
                    const int row = wm + mf * 16 + 4 * (lane >> 4) + r;
                    Ct[row * 68 + nloc] = acc[mf][nf][r];
                }
        }
        __syncthreads();
#pragma unroll
        for (int i = 0; i < 8; ++i) {
            const int idx = tid + i * 256;
            const int row = idx >> 4, f4 = idx & 15;
            const int n = n0 + half * 64 + f4 * 4;
            if (n < NSPEC) {
                const float4 v = *(const float4*)&Ct[row * 68 + f4 * 4];
                *(ush4*)&fftG[(size_t)(m0 + row) * NSPEC + n] = pack4(v);
            }
        }
    }
}

// ---------------- K5: S = sum_d fftU[b,d] * fftG[h,d]; y[b,h,:] = irfft(S)[0:4096] (bf16 out)
// XCD-bijective swizzle: all 8 b of one h land on the same XCD (G row -> L2 hit). ----------------
extern "C" __global__ __launch_bounds__(512) void conv_ifft_k(
    const float2* __restrict__ fftU, const unsigned short* __restrict__ fftG,
    unsigned short* __restrict__ y) {
    __shared__ float2 A[LDSN];
    __shared__ float2 S4096;
    const int wg = blockIdx.x;  // 4096 blocks
    const int h = ((wg & 7) << 6) + (wg >> 6);  // XCD (wg&7) owns h range [x*64, x*64+64)
    const int b = (wg >> 3) & 7;
    const int tid = threadIdx.x;
    const float2* U = fftU + (size_t)b * MD * FS;
    const unsigned short* G = fftG + (size_t)h * MD * NSPEC;
#pragma unroll
    for (int j = 0; j < 9; ++j) {
        const int k = tid + j * 512;
        if (k <= 4096) {
            float2 s = make_float2(0.f, 0.f);
#pragma unroll
            for (int d = 0; d < MD; ++d) {
                const float2 uu = U[d * FS + k];
                const unsigned gv = *(const unsigned*)(G + (size_t)d * NSPEC + 2 * k);
                const float gx = __uint_as_float(gv << 16);
                const float gy = __uint_as_float(gv & 0xFFFF0000u);
                s.x = fmaf(uu.x, gx, fmaf(-uu.y, gy, s.x));
                s.y = fmaf(uu.x, gy, fmaf(uu.y, gx, s.y));
            }
            if (k < 4096) A[PD(k)] = s;
            else S4096 = s;
        }
    }
    __syncthreads();
    float2 Sk[8], Sm[8];
#pragma unroll
    for (int j = 0; j < 8; ++j) {
        const int k = tid + j * 512;
        Sk[j] = A[PD(k)];
        Sm[j] = (k == 0) ? S4096 : A[PD(4096 - k)];
    }
    __syncthreads();
#pragma unroll
    for (int j = 0; j < 8; ++j) {
        const int k = tid + j * 512;
        const float2 E = make_float2(0.5f * (Sk[j].x + Sm[j].x), 0.5f * (Sk[j].y - Sm[j].y));
        const float2 D = make_float2(0.5f * (Sk[j].x - Sm[j].x), 0.5f * (Sk[j].y + Sm[j].y));
        const float2 t = g_tw8192[k];                    // exp(-i*2pi*k/8192)
        const float2 tc = make_float2(t.x, -t.y);        // need +angle here
        const float2 O = cmul(D, tc);
        A[PD(k)] = make_float2(E.x - O.y, E.y + O.x);
    }
    fft4096_ip<1>(A, tid);
    unsigned short* yp = y + (size_t)(b * HID + h) * LSEQ;
    const float inv = 1.0f / 4096.0f;
#pragma unroll
    for (int j = 0; j < 4; ++j) {
        const int n = tid + j * 512;
        const float2 z = A[PD(n)];
        const unsigned pk = (unsigned)f2bf(z.x * inv) | ((unsigned)f2bf(z.y * inv) << 16);
        *(unsigned*)(yp + 2 * n) = pk;  // x[2n], x[2n+1] as bf16 pair
    }
}

// ---------------- K6: h = relu(x @ Whw_x^T + y^T + bias) via bf16 MFMA; also h_last
// XCD swizzle keeps the 4 h-tiles of one m-tile adjacent; reg-staged prefetch K-loop. ----------------
extern "C" __global__ __launch_bounds__(256) void out_gemm_k(
    const unsigned short* __restrict__ x_bf, const unsigned short* __restrict__ Whw_bf,
    const float* __restrict__ Whb, const unsigned short* __restrict__ y,
    float* __restrict__ out) {
    __shared__ __align__(16) char smem[36864];
    short* As = (short*)smem;             // [128][72]
    short* Bs = (short*)(smem + 18432);   // [128][72]
    float* Ys = (float*)smem;             // epilogue: [64][132] (aliased, barrier-separated)
    float* Ct = (float*)smem;             // epilogue: [128][68]

    const int tid = threadIdx.x, lane = tid & 63, wave = tid >> 6;
    // swizzle: 1024 blocks = 8 XCDs * 128; within an XCD, s runs m-major with the 4 h-tiles adjacent
    const int wg = blockIdx.x;
    const int s = ((wg & 7) << 7) + (wg >> 3);
    const int m0 = (s >> 2) * 128;   // 256 m-tiles
    const int h0 = (s & 3) * 128;    // 4 h-tiles
    const int b = m0 >> 12;
    const int t0 = m0 & 4095;

    floatx4 acc[2][8];
#pragma unroll
    for (int i = 0; i < 2; ++i)
#pragma unroll
        for (int j = 0; j < 8; ++j) acc[i][j] = (floatx4){0.f, 0.f, 0.f, 0.f};

    // 16-B/lane staging
    const int lr = tid >> 3;           // 0..31
    const int lc = (tid & 7) * 8;      // 0..56
    const unsigned short* Ap = x_bf + (size_t)(m0 + lr) * INS + lc;
    const unsigned short* Bp = Whw_bf + (size_t)(h0 + lr) * MSZ + 1024 + lc;
    short8 ra[4], rb[4];
#pragma unroll
    for (int i = 0; i < 4; ++i) {
        ra[i] = *(const short8*)(Ap + (size_t)(32 * i) * INS);
        rb[i] = *(const short8*)(Bp + (size_t)(32 * i) * MSZ);
    }

    for (int kc = 0; kc < 4; ++kc) {
#pragma unroll
        for (int i = 0; i < 4; ++i) {
            *(short8*)(&As[(lr + 32 * i) * 72 + lc]) = ra[i];
            *(short8*)(&Bs[(lr + 32 * i) * 72 + lc]) = rb[i];
        }
        __syncthreads();
        if (kc < 3) {
#pragma unroll
            for (int i = 0; i < 4; ++i) {
                ra[i] = *(const short8*)(Ap + (size_t)(32 * i) * INS + (kc + 1) * 64);
                rb[i] = *(const short8*)(Bp + (size_t)(32 * i) * MSZ + (kc + 1) * 64);
            }
        }
        const int arow = (wave * 32 + (lane & 15)) * 72;
        const int brow = (lane & 15) * 72;
        const int kq = 8 * (lane >> 4);
#pragma unroll
        for (int kk = 0; kk < 2; ++kk) {
            const int ko = kk * 32 + kq;
            const short8 a0 = *(const short8*)(&As[arow + ko]);
            const short8 a1 = *(const short8*)(&As[arow + 16 * 72 + ko]);
#pragma unroll
            for (int nf = 0; nf < 8; ++nf) {
                const short8 bv = *(const short8*)(&Bs[brow + nf * 16 * 72 + ko]);
                acc[0][nf] = __builtin_amdgcn_mfma_f32_16x16x32_bf16(a0, bv, acc[0][nf], 0, 0, 0);
                acc[1][nf] = __builtin_amdgcn_mfma_f32_16x16x32_bf16(a1, bv, acc[1][nf], 0, 0, 0);
            }
        }
        __syncthreads();
    }

    // epilogue per 64-h half: stage y^T (bf16->fp32) -> relu(acc+y+bias) in regs
    // -> transpose via LDS -> float4 stores (write-back, line-merged)
    const int wm = wave * 32;
    const int yr = tid >> 5, yc = (tid & 31) * 4;
#pragma unroll 1
    for (int half = 0; half < 2; ++half) {
        __syncthreads();
#pragma unroll
        for (int i = 0; i < 8; ++i) {
            const int hh = yr + 8 * i;
            const ush4 v = *(const ush4*)(y + (size_t)(b * HID + h0 + half * 64 + hh) * LSEQ + t0 + yc);
            Ys[hh * 132 + yc + 0] = bf2f(v.x);
            Ys[hh * 132 + yc + 1] = bf2f(v.y);
            Ys[hh * 132 + yc + 2] = bf2f(v.z);
            Ys[hh * 132 + yc + 3] = bf2f(v.w);
        }
        __syncthreads();
        float v[4][2][4];
#pragma unroll
        for (int nfl = 0; nfl < 4; ++nfl) {
            const int nf = half * 4 + nfl;
            const int hh = nfl * 16 + (lane & 15);
            const float bias = Whb[h0 + half * 64 + hh];
#pragma unroll
            for (int mf = 0; mf < 2; ++mf)
#pragma unroll
                for (int r = 0; r < 4; ++r) {
                    const int row = wm + mf * 16 + 4 * (lane >> 4) + r;
                    v[nfl][mf][r] = fmaxf(acc[mf][nf][r] + Ys[hh * 132 + row] + bias, 0.f);
                }
        }
        __syncthreads();
#pragma unroll
        for (int nfl = 0; nfl < 4; ++nfl) {
            const int nloc = nfl * 16 + (lane & 15);
#pragma unroll
            for (int mf = 0; mf < 2; ++mf)
#pragma unroll
                for (int r = 0; r < 4; ++r) {
                    const int row = wm + mf * 16 + 4 * (lane >> 4) + r;
                    Ct[row * 68 + nloc] = v[nfl][mf][r];
                }
        }
        __syncthreads();
#pragma unroll
        for (int i = 0; i < 8; ++i) {
            const int idx = tid + i * 256;
            const int row = idx >> 4, f4 = idx & 15;
            const floatx4 t = *(const floatx4*)&Ct[row * 68 + f4 * 4];
            *(floatx4*)(out + (size_t)(m0 + row) * HID + h0 + half * 64 + f4 * 4) = t;
            if (((m0 + row) & 4095) == 4095)
                *(floatx4*)(out + (size_t)NB * LSEQ * HID + (size_t)b * HID + h0 + half * 64 + f4 * 4) = t;
        }
    }
}

extern "C" void kernel_launch(void* const* d_in, const int* in_sizes, int n_in,
                              void* d_out, int out_size, void* d_ws, size_t ws_size,
                              hipStream_t stream) {
    const float* x   = (const float*)d_in[0];
    const float* Wuw = (const float*)d_in[1];
    const float* Wub = (const float*)d_in[2];
    const float* Whw = (const float*)d_in[3];
    const float* Whb = (const float*)d_in[4];
    const float* H   = (const float*)d_in[5];
    char* wsb = (char*)d_ws;
    // workspace layout (bytes) — total ~95.5 MB (identical to the verified round-1 layout)
    unsigned short* fftG   = (unsigned short*)(wsb);             // 2048*8256 bf16   = 33,816,576
    unsigned short* yb     = (unsigned short*)(wsb + 33816576);  // 8*512*4096 bf16  = 33,554,432
    float*          fftU   = (float*)(wsb + 67371008);           // 32*4128*2 fp32   =  1,056,768
    unsigned short* fftHT  = (unsigned short*)(wsb + 68427776);  // 8256*256 bf16    =  4,227,072
    float*          ut     = (float*)(wsb + 72654848);           // 32*4096 fp32     =    524,288
    unsigned short* x_bf   = (unsigned short*)(wsb + 73179136);  // 32768*256 bf16   = 16,777,216
    unsigned short* Whw_bf = (unsigned short*)(wsb + 89956352);  // 512*1280 bf16    =  1,310,720
    unsigned short* fftHB  = (unsigned short*)(wsb + 91267072);  // 256*8256 bf16    =  4,227,072
    float* out = (float*)d_out;

    hipLaunchKernelGGL(u_relu_k, dim3(8865), dim3(256), 0, stream, x, Wuw, Wub, ut, x_bf, Whw, Whw_bf);
    hipLaunchKernelGGL(rfft_all_k, dim3(288), dim3(512), 0, stream, ut, H, (float2*)fftU, fftHB);
    hipLaunchKernelGGL(ht2_k, dim3(129, 4), dim3(256), 0, stream, fftHB, fftHT);
    hipLaunchKernelGGL(g_gemm_k, dim3(1040), dim3(256), 0, stream, Whw_bf, fftHT, fftG);
    hipLaunchKernelGGL(conv_ifft_k, dim3(4096), dim3(512), 0, stream,
                       (const float2*)fftU, fftG, yb);
    hipLaunchKernelGGL(out_gemm_k, dim3(1024), dim3(256), 0, stream, x_bf, Whw_bf, Whb, yb, out);
}

// Round 4
// 281.278 us; speedup vs baseline: 1.2856x; 1.2070x over previous
//
#include <hip/hip_runtime.h>

#define NB 8
#define LSEQ 4096
#define INS 256
#define MD 4
#define ORD 256
#define HID 512
#define MSZ 1280
#define FS 4128   // complex stride for spectrum rows (2*FS = 8256 floats)
#define NSPEC 8256
// blocked fftG geometry: [mtile 16][ntile 0..63 full + tail][mloc 128][nloc 128|64]
#define GMT 1056768   // shorts per m-tile: 64*16384 + 8192
#define GNT 16384     // shorts per full n-tile (128*128)

// padded LDS index for FFT kernels: +1 float2 per 8
#define PD(n) ((n) + ((n) >> 3))
#define LDSN 4608

typedef __attribute__((ext_vector_type(8))) short short8;
typedef __attribute__((ext_vector_type(4))) float floatx4;

struct ush4 { unsigned short x, y, z, w; };

// Twiddle tables in code-object device memory (workspace footprint unchanged).
__device__ float2 g_tw4096[4096];   // exp(-2*pi*i*j/4096)
__device__ float2 g_tw8192[4098];   // exp(-2*pi*i*k/8192), k<=4097

__device__ __forceinline__ unsigned short f2bf(float f) {
    unsigned u = __float_as_uint(f);
    u += 0x7FFF + ((u >> 16) & 1);
    return (unsigned short)(u >> 16);
}
__device__ __forceinline__ ush4 pack4(float4 v) {
    ush4 p; p.x = f2bf(v.x); p.y = f2bf(v.y); p.z = f2bf(v.z); p.w = f2bf(v.w); return p;
}
__device__ __forceinline__ float bf2f(unsigned short s) {
    return __uint_as_float(((unsigned)s) << 16);
}

// ---------------- complex helpers ----------------
__device__ __forceinline__ float2 cmul(float2 a, float2 b) {
    return make_float2(fmaf(a.x, b.x, -(a.y * b.y)), fmaf(a.x, b.y, a.y * b.x));
}
__device__ __forceinline__ float2 cadd(float2 a, float2 b) { return make_float2(a.x + b.x, a.y + b.y); }
__device__ __forceinline__ float2 csub(float2 a, float2 b) { return make_float2(a.x - b.x, a.y - b.y); }

template <int DIR>
__device__ __forceinline__ float2 jmul(float2 z) {
    return (DIR < 0) ? make_float2(z.y, -z.x) : make_float2(-z.y, z.x);
}

// In-place Stockham DIF radix-8 stage on padded buffer. 512 threads.
template <int DIR, int N_, int S_>
__device__ __forceinline__ void fft_stage_ip(float2* __restrict__ X, int tid) {
    constexpr int M_ = N_ / 8;
    constexpr int STEP = 4096 / N_;
    const int q = tid & (S_ - 1);
    const int p = tid / S_;
    const int rb = q + S_ * p;
    const float2 a0 = X[PD(rb + S_ * 0 * M_)];
    const float2 a1 = X[PD(rb + S_ * 1 * M_)];
    const float2 a2 = X[PD(rb + S_ * 2 * M_)];
    const float2 a3 = X[PD(rb + S_ * 3 * M_)];
    const float2 a4 = X[PD(rb + S_ * 4 * M_)];
    const float2 a5 = X[PD(rb + S_ * 5 * M_)];
    const float2 a6 = X[PD(rb + S_ * 6 * M_)];
    const float2 a7 = X[PD(rb + S_ * 7 * M_)];

    const int pw = p * STEP;
    float2 w[7];
#pragma unroll
    for (int j = 1; j <= 7; ++j) {
        float2 t = g_tw4096[pw * j];
        if (DIR > 0) t.y = -t.y;
        w[j - 1] = t;
    }

    const float2 e0 = cadd(a0, a4), e1 = csub(a0, a4);
    const float2 e2 = cadd(a2, a6), e3 = jmul<DIR>(csub(a2, a6));
    const float2 E0 = cadd(e0, e2), E2 = csub(e0, e2);
    const float2 E1 = cadd(e1, e3), E3 = csub(e1, e3);
    const float2 f0 = cadd(a1, a5), f1 = csub(a1, a5);
    const float2 f2 = cadd(a3, a7), f3 = jmul<DIR>(csub(a3, a7));
    const float2 O0 = cadd(f0, f2), O2 = csub(f0, f2);
    const float2 O1 = cadd(f1, f3), O3 = csub(f1, f3);

    constexpr float C707 = 0.70710678118654752440f;
    const float2 W1 = make_float2(C707, DIR * C707);
    const float2 W3 = make_float2(-C707, DIR * C707);
    const float2 T1 = cmul(O1, W1);
    const float2 T2 = jmul<DIR>(O2);
    const float2 T3 = cmul(O3, W3);

    const float2 b0 = cadd(E0, O0), b4 = csub(E0, O0);
    const float2 b1 = cadd(E1, T1), b5 = csub(E1, T1);
    const float2 b2 = cadd(E2, T2), b6 = csub(E2, T2);
    const float2 b3 = cadd(E3, T3), b7 = csub(E3, T3);

    __syncthreads();

    const int wb = q + S_ * 8 * p;
    X[PD(wb + 0 * S_)] = b0;
    X[PD(wb + 1 * S_)] = cmul(b1, w[0]);
    X[PD(wb + 2 * S_)] = cmul(b2, w[1]);
    X[PD(wb + 3 * S_)] = cmul(b3, w[2]);
    X[PD(wb + 4 * S_)] = cmul(b4, w[3]);
    X[PD(wb + 5 * S_)] = cmul(b5, w[4]);
    X[PD(wb + 6 * S_)] = cmul(b6, w[5]);
    X[PD(wb + 7 * S_)] = cmul(b7, w[6]);
    __syncthreads();
}

template <int DIR>
__device__ __forceinline__ void fft4096_ip(float2* A, int tid) {
    __syncthreads();
    fft_stage_ip<DIR, 4096, 1>(A, tid);
    fft_stage_ip<DIR, 512, 8>(A, tid);
    fft_stage_ip<DIR, 64, 64>(A, tid);
    fft_stage_ip<DIR, 8, 512>(A, tid);
}

// ---------------- K1: u = relu(x @ Wu_w^T + Wu_b) -> u_t[(b*4+d)][t]; also x_bf = bf16(x).
// x_bf written as 16B/lane fully-contiguous wave stores (even lanes store own+odd-neighbor data).
// Blocks 8192..8831: Whw fp32->bf16 prep. Blocks 8832..8864: twiddle table fill. ----------------
extern "C" __global__ __launch_bounds__(256) void u_relu_k(
    const float* __restrict__ x, const float* __restrict__ Wuw,
    const float* __restrict__ Wub, float* __restrict__ u_t,
    unsigned short* __restrict__ x_bf,
    const float* __restrict__ Whw, unsigned short* __restrict__ Whw_bf) {
    const int blk = blockIdx.x;
    if (blk >= 8832) {
        if (blk < 8848) {
            const int i = (blk - 8832) * 256 + threadIdx.x;  // exactly 4096
            float sn, cs;
            sincosf(-1.53398078788564403e-3f * (float)i, &sn, &cs);  // -2pi/4096
            g_tw4096[i] = make_float2(cs, sn);
        } else {
            const int i = (blk - 8848) * 256 + threadIdx.x;
            if (i <= 4097) {
                float sn, cs;
                sincosf(-7.66990393942820614e-4f * (float)i, &sn, &cs);  // -2pi/8192
                g_tw8192[i] = make_float2(cs, sn);
            }
        }
        return;
    }
    if (blk >= 8192) {
        const int idx = (blk - 8192) * 256 + threadIdx.x;  // 640 blocks: 163840 float4s
        const float4 v = ((const float4*)Whw)[idx];
        *(ush4*)(&Whw_bf[(size_t)idx * 4]) = pack4(v);
        return;
    }
    const int gid = blk * 256 + threadIdx.x;
    const int row = gid >> 6;
    const int lane = threadIdx.x & 63;
    const float4 xv = ((const float4*)x)[(size_t)row * 64 + lane];
    // pack 4 bf16 into 2 dwords; even lanes store 16B covering own + odd neighbor
    unsigned d0 = (unsigned)f2bf(xv.x) | ((unsigned)f2bf(xv.y) << 16);
    unsigned d1 = (unsigned)f2bf(xv.z) | ((unsigned)f2bf(xv.w) << 16);
    const unsigned e0 = (unsigned)__shfl_xor((int)d0, 1);
    const unsigned e1 = (unsigned)__shfl_xor((int)d1, 1);
    if (!(lane & 1)) {
        uint4 v; v.x = d0; v.y = d1; v.z = e0; v.w = e1;
        *(uint4*)(&x_bf[(size_t)row * 256 + lane * 4]) = v;
    }
    const float4 w0 = ((const float4*)Wuw)[0 * 64 + lane];
    const float4 w1 = ((const float4*)Wuw)[1 * 64 + lane];
    const float4 w2 = ((const float4*)Wuw)[2 * 64 + lane];
    const float4 w3 = ((const float4*)Wuw)[3 * 64 + lane];
    float a0 = xv.x * w0.x + xv.y * w0.y + xv.z * w0.z + xv.w * w0.w;
    float a1 = xv.x * w1.x + xv.y * w1.y + xv.z * w1.z + xv.w * w1.w;
    float a2 = xv.x * w2.x + xv.y * w2.y + xv.z * w2.z + xv.w * w2.w;
    float a3 = xv.x * w3.x + xv.y * w3.y + xv.z * w3.z + xv.w * w3.w;
#pragma unroll
    for (int off = 1; off < 64; off <<= 1) {
        a0 += __shfl_xor(a0, off);
        a1 += __shfl_xor(a1, off);
        a2 += __shfl_xor(a2, off);
        a3 += __shfl_xor(a3, off);
    }
    if (lane < 4) {
        float v = (lane == 0) ? a0 : (lane == 1) ? a1 : (lane == 2) ? a2 : a3;
        v = fmaxf(v + Wub[lane], 0.0f);
        const int b = row >> 12, t = row & 4095;
        u_t[((size_t)(b * 4 + lane)) * LSEQ + t] = v;
    }
}

// ---------------- K2: fused rfft. blocks 0..31: u rows -> fftU fp32. blocks 32..287: H rows -> fftHB bf16 row-major ----------------
extern "C" __global__ __launch_bounds__(512) void rfft_all_k(
    const float* __restrict__ ut, const float* __restrict__ H,
    float2* __restrict__ fftU, unsigned short* __restrict__ fftHB) {
    __shared__ float2 A[LDSN];
    const int blk = blockIdx.x;
    const int tid = threadIdx.x;
    const bool is_u = (blk < 32);
    const float* src = is_u ? (ut + (size_t)blk * LSEQ) : (H + (size_t)(blk - 32) * LSEQ);
    const float2* rp = (const float2*)src;
#pragma unroll
    for (int j = 0; j < 8; ++j) {
        const int n = tid + j * 512;
        A[PD(n)] = (n < 2048) ? rp[n] : make_float2(0.f, 0.f);
    }
    fft4096_ip<-1>(A, tid);
    if (is_u) {
        float2* op = fftU + (size_t)blk * FS;
#pragma unroll
        for (int j = 0; j < 9; ++j) {
            const int k = tid + j * 512;
            if (k <= 4096) {
                const float2 Zk = A[PD(k & 4095)];
                const float2 Zm = A[PD((4096 - k) & 4095)];
                const float2 E = make_float2(0.5f * (Zk.x + Zm.x), 0.5f * (Zk.y - Zm.y));
                const float2 D = make_float2(0.5f * (Zk.x - Zm.x), 0.5f * (Zk.y + Zm.y));
                const float2 O = make_float2(D.y, -D.x);
                const float2 t = g_tw8192[k];  // exp(-2*pi*i*k/8192)
                op[k] = cadd(E, cmul(t, O));
            }
        }
    } else {
        const int o = blk - 32;
        unsigned* op = (unsigned*)(fftHB + (size_t)o * NSPEC);  // pair (2k,2k+1) per 4B
#pragma unroll
        for (int j = 0; j < 9; ++j) {
            const int k = tid + j * 512;
            if (k <= 4096) {
                const float2 Zk = A[PD(k & 4095)];
                const float2 Zm = A[PD((4096 - k) & 4095)];
                const float2 E = make_float2(0.5f * (Zk.x + Zm.x), 0.5f * (Zk.y - Zm.y));
                const float2 D = make_float2(0.5f * (Zk.x - Zm.x), 0.5f * (Zk.y + Zm.y));
                const float2 O = make_float2(D.y, -D.x);
                const float2 t = g_tw8192[k];
                const float2 c = cadd(E, cmul(t, O));
                if (2 * k < NSPEC)
                    op[k] = (unsigned)f2bf(c.x) | ((unsigned)f2bf(c.y) << 16);
            }
        }
    }
}

// ---------------- K2b: transpose fftHB [256 o][8256 s] bf16 -> fftHT [8256 s][256 o] bf16 (zero s>=8194) ----------------
extern "C" __global__ __launch_bounds__(256) void ht2_k(
    const unsigned short* __restrict__ fftHB, unsigned short* __restrict__ fftHT) {
    __shared__ unsigned short T[64 * 68];
    const int tid = threadIdx.x;
    const int s0 = blockIdx.x * 64;  // 129 blocks
    const int o0 = blockIdx.y * 64;  // 4 blocks
    const int r = tid >> 4, c4 = (tid & 15) * 4;
#pragma unroll
    for (int i = 0; i < 4; ++i) {
        const int o = r + 16 * i;
        const ush4 v = *(const ush4*)(fftHB + (size_t)(o0 + o) * NSPEC + s0 + c4);
        *(ush4*)(&T[o * 68 + c4]) = v;
    }
    __syncthreads();
#pragma unroll
    for (int i = 0; i < 4; ++i) {
        const int sl = r + 16 * i;
        const int s = s0 + sl;
        ush4 p;
        if (s < 8194) {
            p.x = T[(c4 + 0) * 68 + sl];
            p.y = T[(c4 + 1) * 68 + sl];
            p.z = T[(c4 + 2) * 68 + sl];
            p.w = T[(c4 + 3) * 68 + sl];
        } else { p.x = p.y = p.z = p.w = 0; }
        *(ush4*)(&fftHT[(size_t)s * 256 + o0 + c4]) = p;
    }
}

// ---------------- K4: fftG (BLOCKED layout) = Whw_bf x fftHT^T via bf16 MFMA.
// fftG[mtile][ntile][mloc 128][nloc 128] (tail ntile=64 is 64 wide) so each block's
// output region is fully contiguous -> 1024-B single-segment wave stores.
// n-outer/m-inner XCD swizzle: both m-panels of an XCD visit each B-tile back-to-back. ----------------
extern "C" __global__ __launch_bounds__(256) void g_gemm_k(
    const unsigned short* __restrict__ Whw_bf, const unsigned short* __restrict__ fftHT,
    unsigned short* __restrict__ fftG) {
    __shared__ __align__(16) char smem[36864];
    short* As = (short*)smem;             // [128][72]
    short* Bs = (short*)(smem + 18432);   // [128][72]
    short* Tt = (short*)smem;             // epilogue reuse: bf16 [128][136] = 34816 B

    const int tid = threadIdx.x, lane = tid & 63, wave = tid >> 6;
    // 1040 blocks = 8 XCDs * 130; within XCD: n-tile outer, m-panel (2) inner
    const int wg = blockIdx.x;
    const int loc = wg >> 3;                      // 0..129
    const int mt = (wg & 7) * 2 + (loc & 1);      // m-tile 0..15
    const int nt = loc >> 1;                      // n-tile 0..64
    const int m0 = mt * 128;
    const int n0 = nt * 128;
    floatx4 acc[2][8];
#pragma unroll
    for (int i = 0; i < 2; ++i)
#pragma unroll
        for (int j = 0; j < 8; ++j) acc[i][j] = (floatx4){0.f, 0.f, 0.f, 0.f};

    // 16-B/lane staging: 32 rows per pass, 4 passes cover 128 rows x 64 k
    const int lr = tid >> 3;           // 0..31
    const int lc = (tid & 7) * 8;      // bf16 col: 0..56
    short8 ra[4], rb[4];

#define GL_A(kc, i) (*(const short8*)(Whw_bf + (size_t)((m0 + lr + 32 * (i)) >> 2) * MSZ + ((m0 + lr + 32 * (i)) & 3) * 256 + (kc) * 64 + lc))
#pragma unroll
    for (int i = 0; i < 4; ++i) {
        ra[i] = GL_A(0, i);
        const int n = n0 + lr + 32 * i;
        rb[i] = (n < NSPEC) ? *(const short8*)(fftHT + (size_t)n * 256 + lc)
                            : (short8){0, 0, 0, 0, 0, 0, 0, 0};
    }

    for (int kc = 0; kc < 4; ++kc) {
#pragma unroll
        for (int i = 0; i < 4; ++i) {
            *(short8*)(&As[(lr + 32 * i) * 72 + lc]) = ra[i];
            *(short8*)(&Bs[(lr + 32 * i) * 72 + lc]) = rb[i];
        }
        __syncthreads();
        if (kc < 3) {
#pragma unroll
            for (int i = 0; i < 4; ++i) {
                ra[i] = GL_A(kc + 1, i);
                const int n = n0 + lr + 32 * i;
                rb[i] = (n < NSPEC) ? *(const short8*)(fftHT + (size_t)n * 256 + (kc + 1) * 64 + lc)
                                    : (short8){0, 0, 0, 0, 0, 0, 0, 0};
            }
        }
        const int arow = (wave * 32 + (lane & 15)) * 72;
        const int brow = (lane & 15) * 72;
        const int kq = 8 * (lane >> 4);
#pragma unroll
        for (int kk = 0; kk < 2; ++kk) {
            const int ko = kk * 32 + kq;
            const short8 a0 = *(const short8*)(&As[arow + ko]);
            const short8 a1 = *(const short8*)(&As[arow + 16 * 72 + ko]);
#pragma unroll
            for (int nf = 0; nf < 8; ++nf) {
                const short8 bv = *(const short8*)(&Bs[brow + nf * 16 * 72 + ko]);
                acc[0][nf] = __builtin_amdgcn_mfma_f32_16x16x32_bf16(a0, bv, acc[0][nf], 0, 0, 0);
                acc[1][nf] = __builtin_amdgcn_mfma_f32_16x16x32_bf16(a1, bv, acc[1][nf], 0, 0, 0);
            }
        }
        __syncthreads();
    }
#undef GL_A
    // epilogue: pack to bf16 tile [128][136] in LDS, then fully-contiguous 16B stores
    const int wm = wave * 32;
#pragma unroll
    for (int mf = 0; mf < 2; ++mf) {
        const int row = wm + mf * 16 + 4 * (lane >> 4);
#pragma unroll
        for (int nf = 0; nf < 8; ++nf) {
            const int col = nf * 16 + (lane & 15);
#pragma unroll
            for (int r = 0; r < 4; ++r)
                Tt[(row + r) * 136 + col] = (short)f2bf(acc[mf][nf][r]);
        }
    }
    __syncthreads();
    const size_t gb = (size_t)mt * GMT + (size_t)nt * GNT;
    if (n0 < 8192) {
#pragma unroll
        for (int i = 0; i < 8; ++i) {
            const int idx = tid + i * 256;        // [0,2048): offset = idx*8 shorts (linear!)
            const int ml = idx >> 4, c8 = (idx & 15) * 8;
            const short8 v = *(const short8*)(&Tt[ml * 136 + c8]);
            *(short8*)(&fftG[gb + (size_t)idx * 8]) = v;
        }
    } else {
        // tail tile: 64-wide
#pragma unroll
        for (int i = 0; i < 4; ++i) {
            const int idx = tid + i * 256;        // [0,1024)
            const int ml = idx >> 3, c8 = (idx & 7) * 8;
            const short8 v = *(const short8*)(&Tt[ml * 136 + c8]);
            *(short8*)(&fftG[gb + (size_t)idx * 8]) = v;
        }
    }
}

// ---------------- K5: S = sum_d fftU[b,d] * fftG[h,d]; y[b,h,:] = irfft(S)[0:4096] (bf16 out)
// Reads blocked fftG (wave-contiguous); writes yb as 16B/lane single-segment wave stores.
// XCD-bijective swizzle: all 8 b of one h land on the same XCD (G row -> L2 hit). ----------------
extern "C" __global__ __launch_bounds__(512) void conv_ifft_k(
    const float2* __restrict__ fftU, const unsigned short* __restrict__ fftG,
    unsigned short* __restrict__ y) {
    __shared__ float2 A[LDSN];
    __shared__ float2 S4096;
    const int wg = blockIdx.x;  // 4096 blocks
    const int h = ((wg & 7) << 6) + (wg >> 6);  // XCD (wg&7) owns h range [x*64, x*64+64)
    const int b = (wg >> 3) & 7;
    const int tid = threadIdx.x;
    const float2* U = fftU + (size_t)b * MD * FS;
    // blocked G: mtile = h>>5, mloc = (h&31)*4 + d
    const size_t mbase = (size_t)(h >> 5) * GMT + (size_t)((h & 31) * 4) * 128;
    const size_t tail = (size_t)(h >> 5) * GMT + (size_t)64 * GNT + (size_t)((h & 31) * 4) * 64;
#pragma unroll
    for (int j = 0; j < 9; ++j) {
        const int k = tid + j * 512;
        if (k <= 4096) {
            float2 s = make_float2(0.f, 0.f);
#pragma unroll
            for (int d = 0; d < MD; ++d) {
                const unsigned gv = (k < 4096)
                    ? *(const unsigned*)(fftG + mbase + (size_t)d * 128 + (size_t)(k >> 6) * GNT + (k & 63) * 2)
                    : *(const unsigned*)(fftG + tail + (size_t)d * 64);
                const float2 uu = U[d * FS + k];
                const float gx = __uint_as_float(gv << 16);
                const float gy = __uint_as_float(gv & 0xFFFF0000u);
                s.x = fmaf(uu.x, gx, fmaf(-uu.y, gy, s.x));
                s.y = fmaf(uu.x, gy, fmaf(uu.y, gx, s.y));
            }
            if (k < 4096) A[PD(k)] = s;
            else S4096 = s;
        }
    }
    __syncthreads();
    float2 Sk[8], Sm[8];
#pragma unroll
    for (int j = 0; j < 8; ++j) {
        const int k = tid + j * 512;
        Sk[j] = A[PD(k)];
        Sm[j] = (k == 0) ? S4096 : A[PD(4096 - k)];
    }
    __syncthreads();
#pragma unroll
    for (int j = 0; j < 8; ++j) {
        const int k = tid + j * 512;
        const float2 E = make_float2(0.5f * (Sk[j].x + Sm[j].x), 0.5f * (Sk[j].y - Sm[j].y));
        const float2 D = make_float2(0.5f * (Sk[j].x - Sm[j].x), 0.5f * (Sk[j].y + Sm[j].y));
        const float2 t = g_tw8192[k];                    // exp(-i*2pi*k/8192)
        const float2 tc = make_float2(t.x, -t.y);        // need +angle here
        const float2 O = cmul(D, tc);
        A[PD(k)] = make_float2(E.x - O.y, E.y + O.x);
    }
    fft4096_ip<1>(A, tid);
    unsigned short* yp = y + (size_t)(b * HID + h) * LSEQ;
    const float inv = 1.0f / 4096.0f;
    {
        const int q = tid;  // 512 threads x 16B = 8192 B = full row
        unsigned dw[4];
#pragma unroll
        for (int jj = 0; jj < 4; ++jj) {
            const float2 z = A[PD(4 * q + jj)];
            dw[jj] = (unsigned)f2bf(z.x * inv) | ((unsigned)f2bf(z.y * inv) << 16);
        }
        uint4 v; v.x = dw[0]; v.y = dw[1]; v.z = dw[2]; v.w = dw[3];
        *(uint4*)(yp + 8 * q) = v;  // x[8q..8q+7] bf16
    }
}

// ---------------- K6: h = relu(x @ Whw_x^T + y^T + bias) via bf16 MFMA; also h_last
// (unchanged this round — control for the store-contiguity experiment) ----------------
extern "C" __global__ __launch_bounds__(256) void out_gemm_k(
    const unsigned short* __restrict__ x_bf, const unsigned short* __restrict__ Whw_bf,
    const float* __restrict__ Whb, const unsigned short* __restrict__ y,
    float* __restrict__ out) {
    __shared__ __align__(16) char smem[36864];
    short* As = (short*)smem;             // [128][72]
    short* Bs = (short*)(smem + 18432);   // [128][72]
    float* Ys = (float*)smem;             // epilogue: [64][132] (aliased, barrier-separated)
    float* Ct = (float*)smem;             // epilogue: [128][68]

    const int tid = threadIdx.x, lane = tid & 63, wave = tid >> 6;
    const int wg = blockIdx.x;
    const int s = ((wg & 7) << 7) + (wg >> 3);
    const int m0 = (s >> 2) * 128;   // 256 m-tiles
    const int h0 = (s & 3) * 128;    // 4 h-tiles
    const int b = m0 >> 12;
    const int t0 = m0 & 4095;

    floatx4 acc[2][8];
#pragma unroll
    for (int i = 0; i < 2; ++i)
#pragma unroll
        for (int j = 0; j < 8; ++j) acc[i][j] = (floatx4){0.f, 0.f, 0.f, 0.f};

    const int lr = tid >> 3;           // 0..31
    const int lc = (tid & 7) * 8;      // 0..56
    const unsigned short* Ap = x_bf + (size_t)(m0 + lr) * INS + lc;
    const unsigned short* Bp = Whw_bf + (size_t)(h0 + lr) * MSZ + 1024 + lc;
    short8 ra[4], rb[4];
#pragma unroll
    for (int i = 0; i < 4; ++i) {
        ra[i] = *(const short8*)(Ap + (size_t)(32 * i) * INS);
        rb[i] = *(const short8*)(Bp + (size_t)(32 * i) * MSZ);
    }

    for (int kc = 0; kc < 4; ++kc) {
#pragma unroll
        for (int i = 0; i < 4; ++i) {
            *(short8*)(&As[(lr + 32 * i) * 72 + lc]) = ra[i];
            *(short8*)(&Bs[(lr + 32 * i) * 72 + lc]) = rb[i];
        }
        __syncthreads();
        if (kc < 3) {
#pragma unroll
            for (int i = 0; i < 4; ++i) {
                ra[i] = *(const short8*)(Ap + (size_t)(32 * i) * INS + (kc + 1) * 64);
                rb[i] = *(const short8*)(Bp + (size_t)(32 * i) * MSZ + (kc + 1) * 64);
            }
        }
        const int arow = (wave * 32 + (lane & 15)) * 72;
        const int brow = (lane & 15) * 72;
        const int kq = 8 * (lane >> 4);
#pragma unroll
        for (int kk = 0; kk < 2; ++kk) {
            const int ko = kk * 32 + kq;
            const short8 a0 = *(const short8*)(&As[arow + ko]);
            const short8 a1 = *(const short8*)(&As[arow + 16 * 72 + ko]);
#pragma unroll
            for (int nf = 0; nf < 8; ++nf) {
                const short8 bv = *(const short8*)(&Bs[brow + nf * 16 * 72 + ko]);
                acc[0][nf] = __builtin_amdgcn_mfma_f32_16x16x32_bf16(a0, bv, acc[0][nf], 0, 0, 0);
                acc[1][nf] = __builtin_amdgcn_mfma_f32_16x16x32_bf16(a1, bv, acc[1][nf], 0, 0, 0);
            }
        }
        __syncthreads();
    }

    const int wm = wave * 32;
    const int yr = tid >> 5, yc = (tid & 31) * 4;
#pragma unroll 1
    for (int half = 0; half < 2; ++half) {
        __syncthreads();
#pragma unroll
        for (int i = 0; i < 8; ++i) {
            const int hh = yr + 8 * i;
            const ush4 v = *(const ush4*)(y + (size_t)(b * HID + h0 + half * 64 + hh) * LSEQ + t0 + yc);
            Ys[hh * 132 + yc + 0] = bf2f(v.x);
            Ys[hh * 132 + yc + 1] = bf2f(v.y);
            Ys[hh * 132 + yc + 2] = bf2f(v.z);
            Ys[hh * 132 + yc + 3] = bf2f(v.w);
        }
        __syncthreads();
        float v[4][2][4];
#pragma unroll
        for (int nfl = 0; nfl < 4; ++nfl) {
            const int nf = half * 4 + nfl;
            const int hh = nfl * 16 + (lane & 15);
            const float bias = Whb[h0 + half * 64 + hh];
#pragma unroll
            for (int mf = 0; mf < 2; ++mf)
#pragma unroll
                for (int r = 0; r < 4; ++r) {
                    const int row = wm + mf * 16 + 4 * (lane >> 4) + r;
                    v[nfl][mf][r] = fmaxf(acc[mf][nf][r] + Ys[hh * 132 + row] + bias, 0.f);
                }
        }
        __syncthreads();
#pragma unroll
        for (int nfl = 0; nfl < 4; ++nfl) {
            const int nloc = nfl * 16 + (lane & 15);
#pragma unroll
            for (int mf = 0; mf < 2; ++mf)
#pragma unroll
                for (int r = 0; r < 4; ++r) {
                    const int row = wm + mf * 16 + 4 * (lane >> 4) + r;
                    Ct[row * 68 + nloc] = v[nfl][mf][r];
                }
        }
        __syncthreads();
#pragma unroll
        for (int i = 0; i < 8; ++i) {
            const int idx = tid + i * 256;
            const int row = idx >> 4, f4 = idx & 15;
            const floatx4 t = *(const floatx4*)&Ct[row * 68 + f4 * 4];
            *(floatx4*)(out + (size_t)(m0 + row) * HID + h0 + half * 64 + f4 * 4) = t;
            if (((m0 + row) & 4095) == 4095)
                *(floatx4*)(out + (size_t)NB * LSEQ * HID + (size_t)b * HID + h0 + half * 64 + f4 * 4) = t;
        }
    }
}

extern "C" void kernel_launch(void* const* d_in, const int* in_sizes, int n_in,
                              void* d_out, int out_size, void* d_ws, size_t ws_size,
                              hipStream_t stream) {
    const float* x   = (const float*)d_in[0];
    const float* Wuw = (const float*)d_in[1];
    const float* Wub = (const float*)d_in[2];
    const float* Whw = (const float*)d_in[3];
    const float* Whb = (const float*)d_in[4];
    const float* H   = (const float*)d_in[5];
    char* wsb = (char*)d_ws;
    // workspace layout (bytes) — identical footprint to the verified round-1 layout
    unsigned short* fftG   = (unsigned short*)(wsb);             // blocked, 33,816,576 B (same size)
    unsigned short* yb     = (unsigned short*)(wsb + 33816576);  // 8*512*4096 bf16  = 33,554,432
    float*          fftU   = (float*)(wsb + 67371008);           // 32*4128*2 fp32   =  1,056,768
    unsigned short* fftHT  = (unsigned short*)(wsb + 68427776);  // 8256*256 bf16    =  4,227,072
    float*          ut     = (float*)(wsb + 72654848);           // 32*4096 fp32     =    524,288
    unsigned short* x_bf   = (unsigned short*)(wsb + 73179136);  // 32768*256 bf16   = 16,777,216
    unsigned short* Whw_bf = (unsigned short*)(wsb + 89956352);  // 512*1280 bf16    =  1,310,720
    unsigned short* fftHB  = (unsigned short*)(wsb + 91267072);  // 256*8256 bf16    =  4,227,072
    float* out = (float*)d_out;

    hipLaunchKernelGGL(u_relu_k, dim3(8865), dim3(256), 0, stream, x, Wuw, Wub, ut, x_bf, Whw, Whw_bf);
    hipLaunchKernelGGL(rfft_all_k, dim3(288), dim3(512), 0, stream, ut, H, (float2*)fftU, fftHB);
    hipLaunchKernelGGL(ht2_k, dim3(129, 4), dim3(256), 0, stream, fftHB, fftHT);
    hipLaunchKernelGGL(g_gemm_k, dim3(1040), dim3(256), 0, stream, Whw_bf, fftHT, fftG);
    hipLaunchKernelGGL(conv_ifft_k, dim3(4096), dim3(512), 0, stream,
                       (const float2*)fftU, fftG, yb);
    hipLaunchKernelGGL(out_gemm_k, dim3(1024), dim3(256), 0, stream, x_bf, Whw_bf, Whb, yb, out);
}

// Round 5
// 245.474 us; speedup vs baseline: 1.4731x; 1.1459x over previous
//
#include <hip/hip_runtime.h>

#define NB 8
#define LSEQ 4096
#define INS 256
#define MD 4
#define ORD 256
#define HID 512
#define MSZ 1280
#define FS 4128   // complex stride for spectrum rows (2*FS = 8256 floats)
#define NSPEC 8256
// blocked fftG geometry: [mtile 16][ntile 0..63 full + tail][mloc 128][nloc 128|64]
#define GMT 1056768   // shorts per m-tile: 64*16384 + 8192
#define GNT 16384     // shorts per full n-tile (128*128)

// padded LDS index for FFT kernels: +1 float2 per 8
#define PD(n) ((n) + ((n) >> 3))
#define LDSN 4608

typedef __attribute__((ext_vector_type(8))) short short8;
typedef __attribute__((ext_vector_type(4))) float floatx4;

struct ush4 { unsigned short x, y, z, w; };

// Twiddle tables in code-object device memory (workspace footprint unchanged).
__device__ float2 g_tw4096[4096];   // exp(-2*pi*i*j/4096)
__device__ float2 g_tw8192[4098];   // exp(-2*pi*i*k/8192), k<=4097

__device__ __forceinline__ unsigned short f2bf(float f) {
    unsigned u = __float_as_uint(f);
    u += 0x7FFF + ((u >> 16) & 1);
    return (unsigned short)(u >> 16);
}
__device__ __forceinline__ ush4 pack4(float4 v) {
    ush4 p; p.x = f2bf(v.x); p.y = f2bf(v.y); p.z = f2bf(v.z); p.w = f2bf(v.w); return p;
}
__device__ __forceinline__ float bf2f(unsigned short s) {
    return __uint_as_float(((unsigned)s) << 16);
}

// ---------------- complex helpers ----------------
__device__ __forceinline__ float2 cmul(float2 a, float2 b) {
    return make_float2(fmaf(a.x, b.x, -(a.y * b.y)), fmaf(a.x, b.y, a.y * b.x));
}
__device__ __forceinline__ float2 cadd(float2 a, float2 b) { return make_float2(a.x + b.x, a.y + b.y); }
__device__ __forceinline__ float2 csub(float2 a, float2 b) { return make_float2(a.x - b.x, a.y - b.y); }

template <int DIR>
__device__ __forceinline__ float2 jmul(float2 z) {
    return (DIR < 0) ? make_float2(z.y, -z.x) : make_float2(-z.y, z.x);
}

// radix-8 butterfly on 8 registers (identical math to fft_stage_ip's core)
template <int DIR>
__device__ __forceinline__ void bfly8(const float2* a, float2* b) {
    const float2 e0 = cadd(a[0], a[4]), e1 = csub(a[0], a[4]);
    const float2 e2 = cadd(a[2], a[6]), e3 = jmul<DIR>(csub(a[2], a[6]));
    const float2 E0 = cadd(e0, e2), E2 = csub(e0, e2);
    const float2 E1 = cadd(e1, e3), E3 = csub(e1, e3);
    const float2 f0 = cadd(a[1], a[5]), f1 = csub(a[1], a[5]);
    const float2 f2 = cadd(a[3], a[7]), f3 = jmul<DIR>(csub(a[3], a[7]));
    const float2 O0 = cadd(f0, f2), O2 = csub(f0, f2);
    const float2 O1 = cadd(f1, f3), O3 = csub(f1, f3);
    constexpr float C707 = 0.70710678118654752440f;
    const float2 W1 = make_float2(C707, DIR * C707);
    const float2 W3 = make_float2(-C707, DIR * C707);
    const float2 T1 = cmul(O1, W1);
    const float2 T2 = jmul<DIR>(O2);
    const float2 T3 = cmul(O3, W3);
    b[0] = cadd(E0, O0); b[4] = csub(E0, O0);
    b[1] = cadd(E1, T1); b[5] = csub(E1, T1);
    b[2] = cadd(E2, T2); b[6] = csub(E2, T2);
    b[3] = cadd(E3, T3); b[7] = csub(E3, T3);
}

// In-place Stockham DIF radix-8 stage on padded buffer. 512 threads.
template <int DIR, int N_, int S_>
__device__ __forceinline__ void fft_stage_ip(float2* __restrict__ X, int tid) {
    constexpr int M_ = N_ / 8;
    constexpr int STEP = 4096 / N_;
    const int q = tid & (S_ - 1);
    const int p = tid / S_;
    const int rb = q + S_ * p;
    float2 a[8], b[8];
#pragma unroll
    for (int l = 0; l < 8; ++l) a[l] = X[PD(rb + S_ * l * M_)];

    const int pw = p * STEP;
    float2 w[7];
#pragma unroll
    for (int j = 1; j <= 7; ++j) {
        float2 t = g_tw4096[pw * j];
        if (DIR > 0) t.y = -t.y;
        w[j - 1] = t;
    }

    bfly8<DIR>(a, b);

    __syncthreads();

    const int wb = q + S_ * 8 * p;
    X[PD(wb + 0 * S_)] = b[0];
#pragma unroll
    for (int j = 1; j < 8; ++j)
        X[PD(wb + j * S_)] = cmul(b[j], w[j - 1]);
    __syncthreads();
}

// ---------------- K1: u = relu(x @ Wu_w^T + Wu_b) -> u_t[(b*4+d)][t]; also x_bf = bf16(x).
// Blocks 8192..8703: Whw d-part -> Whw_bf [512][1024] bf16.
// Blocks 8704..8831: Whw x-part -> Wt [8 kc][512 h][32 k] bf16 (k-chunked, h-major).
// Blocks 8832..8864: twiddle table fill. ----------------
extern "C" __global__ __launch_bounds__(256) void u_relu_k(
    const float* __restrict__ x, const float* __restrict__ Wuw,
    const float* __restrict__ Wub, float* __restrict__ u_t,
    unsigned short* __restrict__ x_bf,
    const float* __restrict__ Whw, unsigned short* __restrict__ Whw_bf,
    unsigned short* __restrict__ Wt) {
    const int blk = blockIdx.x;
    if (blk >= 8832) {
        if (blk < 8848) {
            const int i = (blk - 8832) * 256 + threadIdx.x;  // exactly 4096
            float sn, cs;
            sincosf(-1.53398078788564403e-3f * (float)i, &sn, &cs);  // -2pi/4096
            g_tw4096[i] = make_float2(cs, sn);
        } else {
            const int i = (blk - 8848) * 256 + threadIdx.x;
            if (i <= 4097) {
                float sn, cs;
                sincosf(-7.66990393942820614e-4f * (float)i, &sn, &cs);  // -2pi/8192
                g_tw8192[i] = make_float2(cs, sn);
            }
        }
        return;
    }
    if (blk >= 8704) {
        // Wt: dst linear = c*16384 + h*32 + kk ; src = Whw[h*1280 + 1024 + c*32 + kk]
        const int didx = (blk - 8704) * 1024 + threadIdx.x * 4;  // 128 blocks x 1024
        const int c = didx >> 14;
        const int r = didx & 16383;
        const int h = r >> 5, kk = r & 31;
        const float4 v = *(const float4*)(Whw + (size_t)h * MSZ + 1024 + c * 32 + kk);
        *(ush4*)(&Wt[didx]) = pack4(v);
        return;
    }
    if (blk >= 8192) {
        // d-part: [512][1024] bf16, linear float4 copy of cols 0..1023
        const int idx = (blk - 8192) * 256 + threadIdx.x;  // 512 blocks: 131072 float4s
        const int h = idx >> 8, c = idx & 255;
        const float4 v = ((const float4*)Whw)[(size_t)h * 320 + c];
        *(ush4*)(&Whw_bf[(size_t)idx * 4]) = pack4(v);
        return;
    }
    const int gid = blk * 256 + threadIdx.x;
    const int row = gid >> 6;
    const int lane = threadIdx.x & 63;
    const float4 xv = ((const float4*)x)[(size_t)row * 64 + lane];
    // pack 4 bf16 into 2 dwords; even lanes store 16B covering own + odd neighbor
    unsigned d0 = (unsigned)f2bf(xv.x) | ((unsigned)f2bf(xv.y) << 16);
    unsigned d1 = (unsigned)f2bf(xv.z) | ((unsigned)f2bf(xv.w) << 16);
    const unsigned e0 = (unsigned)__shfl_xor((int)d0, 1);
    const unsigned e1 = (unsigned)__shfl_xor((int)d1, 1);
    if (!(lane & 1)) {
        uint4 v; v.x = d0; v.y = d1; v.z = e0; v.w = e1;
        *(uint4*)(&x_bf[(size_t)row * 256 + lane * 4]) = v;
    }
    const float4 w0 = ((const float4*)Wuw)[0 * 64 + lane];
    const float4 w1 = ((const float4*)Wuw)[1 * 64 + lane];
    const float4 w2 = ((const float4*)Wuw)[2 * 64 + lane];
    const float4 w3 = ((const float4*)Wuw)[3 * 64 + lane];
    float a0 = xv.x * w0.x + xv.y * w0.y + xv.z * w0.z + xv.w * w0.w;
    float a1 = xv.x * w1.x + xv.y * w1.y + xv.z * w1.z + xv.w * w1.w;
    float a2 = xv.x * w2.x + xv.y * w2.y + xv.z * w2.z + xv.w * w2.w;
    float a3 = xv.x * w3.x + xv.y * w3.y + xv.z * w3.z + xv.w * w3.w;
#pragma unroll
    for (int off = 1; off < 64; off <<= 1) {
        a0 += __shfl_xor(a0, off);
        a1 += __shfl_xor(a1, off);
        a2 += __shfl_xor(a2, off);
        a3 += __shfl_xor(a3, off);
    }
    if (lane < 4) {
        float v = (lane == 0) ? a0 : (lane == 1) ? a1 : (lane == 2) ? a2 : a3;
        v = fmaxf(v + Wub[lane], 0.0f);
        const int b = row >> 12, t = row & 4095;
        u_t[((size_t)(b * 4 + lane)) * LSEQ + t] = v;
    }
}

// ---------------- K2: fused rfft. blocks 0..31: u rows -> fftU fp32. blocks 32..287: H rows -> fftHB bf16.
// Stage 1 fused into the input load (register butterfly). ----------------
extern "C" __global__ __launch_bounds__(512) void rfft_all_k(
    const float* __restrict__ ut, const float* __restrict__ H,
    float2* __restrict__ fftU, unsigned short* __restrict__ fftHB) {
    __shared__ float2 A[LDSN];
    const int blk = blockIdx.x;
    const int tid = threadIdx.x;
    const bool is_u = (blk < 32);
    const float* src = is_u ? (ut + (size_t)blk * LSEQ) : (H + (size_t)(blk - 32) * LSEQ);
    const float2* rp = (const float2*)src;
    // fused stage 1 (p = tid, elements tid + 512j live in registers; j>=4 are zero-pad)
    {
        float2 c[8], b[8];
#pragma unroll
        for (int j = 0; j < 4; ++j) c[j] = rp[tid + j * 512];
#pragma unroll
        for (int j = 4; j < 8; ++j) c[j] = make_float2(0.f, 0.f);
        bfly8<-1>(c, b);
        A[PD(8 * tid + 0)] = b[0];
#pragma unroll
        for (int j = 1; j < 8; ++j)
            A[PD(8 * tid + j)] = cmul(b[j], g_tw4096[tid * j]);
    }
    __syncthreads();
    fft_stage_ip<-1, 512, 8>(A, tid);
    fft_stage_ip<-1, 64, 64>(A, tid);
    fft_stage_ip<-1, 8, 512>(A, tid);
    if (is_u) {
        float2* op = fftU + (size_t)blk * FS;
#pragma unroll
        for (int j = 0; j < 9; ++j) {
            const int k = tid + j * 512;
            if (k <= 4096) {
                const float2 Zk = A[PD(k & 4095)];
                const float2 Zm = A[PD((4096 - k) & 4095)];
                const float2 E = make_float2(0.5f * (Zk.x + Zm.x), 0.5f * (Zk.y - Zm.y));
                const float2 D = make_float2(0.5f * (Zk.x - Zm.x), 0.5f * (Zk.y + Zm.y));
                const float2 O = make_float2(D.y, -D.x);
                const float2 t = g_tw8192[k];  // exp(-2*pi*i*k/8192)
                op[k] = cadd(E, cmul(t, O));
            }
        }
    } else {
        const int o = blk - 32;
        unsigned* op = (unsigned*)(fftHB + (size_t)o * NSPEC);  // pair (2k,2k+1) per 4B
#pragma unroll
        for (int j = 0; j < 9; ++j) {
            const int k = tid + j * 512;
            if (k <= 4096) {
                const float2 Zk = A[PD(k & 4095)];
                const float2 Zm = A[PD((4096 - k) & 4095)];
                const float2 E = make_float2(0.5f * (Zk.x + Zm.x), 0.5f * (Zk.y - Zm.y));
                const float2 D = make_float2(0.5f * (Zk.x - Zm.x), 0.5f * (Zk.y + Zm.y));
                const float2 O = make_float2(D.y, -D.x);
                const float2 t = g_tw8192[k];
                const float2 c = cadd(E, cmul(t, O));
                if (2 * k < NSPEC)
                    op[k] = (unsigned)f2bf(c.x) | ((unsigned)f2bf(c.y) << 16);
            }
        }
    }
}

// ---------------- K2b: transpose fftHB [256 o][8256 s] bf16 -> fftHT [8256 s][256 o] bf16 (zero s>=8194) ----------------
extern "C" __global__ __launch_bounds__(256) void ht2_k(
    const unsigned short* __restrict__ fftHB, unsigned short* __restrict__ fftHT) {
    __shared__ unsigned short T[64 * 68];
    const int tid = threadIdx.x;
    const int s0 = blockIdx.x * 64;  // 129 blocks
    const int o0 = blockIdx.y * 64;  // 4 blocks
    const int r = tid >> 4, c4 = (tid & 15) * 4;
#pragma unroll
    for (int i = 0; i < 4; ++i) {
        const int o = r + 16 * i;
        const ush4 v = *(const ush4*)(fftHB + (size_t)(o0 + o) * NSPEC + s0 + c4);
        *(ush4*)(&T[o * 68 + c4]) = v;
    }
    __syncthreads();
#pragma unroll
    for (int i = 0; i < 4; ++i) {
        const int sl = r + 16 * i;
        const int s = s0 + sl;
        ush4 p;
        if (s < 8194) {
            p.x = T[(c4 + 0) * 68 + sl];
            p.y = T[(c4 + 1) * 68 + sl];
            p.z = T[(c4 + 2) * 68 + sl];
            p.w = T[(c4 + 3) * 68 + sl];
        } else { p.x = p.y = p.z = p.w = 0; }
        *(ush4*)(&fftHT[(size_t)s * 256 + o0 + c4]) = p;
    }
}

// ---------------- K4: fftG (blocked) = Whw_bf x fftHT^T via bf16 MFMA.
// Whw_bf is now [512 h][1024] (d-part only). Contiguous 1024-B wave stores. ----------------
extern "C" __global__ __launch_bounds__(256) void g_gemm_k(
    const unsigned short* __restrict__ Whw_bf, const unsigned short* __restrict__ fftHT,
    unsigned short* __restrict__ fftG) {
    __shared__ __align__(16) char smem[36864];
    short* As = (short*)smem;             // [128][72]
    short* Bs = (short*)(smem + 18432);   // [128][72]
    short* Tt = (short*)smem;             // epilogue reuse: bf16 [128][136] = 34816 B

    const int tid = threadIdx.x, lane = tid & 63, wave = tid >> 6;
    // 1040 blocks = 8 XCDs * 130; within XCD: n-tile outer, m-panel (2) inner
    const int wg = blockIdx.x;
    const int loc = wg >> 3;                      // 0..129
    const int mt = (wg & 7) * 2 + (loc & 1);      // m-tile 0..15
    const int nt = loc >> 1;                      // n-tile 0..64
    const int m0 = mt * 128;
    const int n0 = nt * 128;
    floatx4 acc[2][8];
#pragma unroll
    for (int i = 0; i < 2; ++i)
#pragma unroll
        for (int j = 0; j < 8; ++j) acc[i][j] = (floatx4){0.f, 0.f, 0.f, 0.f};

    const int lr = tid >> 3;           // 0..31
    const int lc = (tid & 7) * 8;      // bf16 col: 0..56
    short8 ra[4], rb[4];

#define GL_A(kc, i) (*(const short8*)(Whw_bf + (size_t)((m0 + lr + 32 * (i)) >> 2) * 1024 + ((m0 + lr + 32 * (i)) & 3) * 256 + (kc) * 64 + lc))
#pragma unroll
    for (int i = 0; i < 4; ++i) {
        ra[i] = GL_A(0, i);
        const int n = n0 + lr + 32 * i;
        rb[i] = (n < NSPEC) ? *(const short8*)(fftHT + (size_t)n * 256 + lc)
                            : (short8){0, 0, 0, 0, 0, 0, 0, 0};
    }

    for (int kc = 0; kc < 4; ++kc) {
#pragma unroll
        for (int i = 0; i < 4; ++i) {
            *(short8*)(&As[(lr + 32 * i) * 72 + lc]) = ra[i];
            *(short8*)(&Bs[(lr + 32 * i) * 72 + lc]) = rb[i];
        }
        __syncthreads();
        if (kc < 3) {
#pragma unroll
            for (int i = 0; i < 4; ++i) {
                ra[i] = GL_A(kc + 1, i);
                const int n = n0 + lr + 32 * i;
                rb[i] = (n < NSPEC) ? *(const short8*)(fftHT + (size_t)n * 256 + (kc + 1) * 64 + lc)
                                    : (short8){0, 0, 0, 0, 0, 0, 0, 0};
            }
        }
        const int arow = (wave * 32 + (lane & 15)) * 72;
        const int brow = (lane & 15) * 72;
        const int kq = 8 * (lane >> 4);
#pragma unroll
        for (int kk = 0; kk < 2; ++kk) {
            const int ko = kk * 32 + kq;
            const short8 a0 = *(const short8*)(&As[arow + ko]);
            const short8 a1 = *(const short8*)(&As[arow + 16 * 72 + ko]);
#pragma unroll
            for (int nf = 0; nf < 8; ++nf) {
                const short8 bv = *(const short8*)(&Bs[brow + nf * 16 * 72 + ko]);
                acc[0][nf] = __builtin_amdgcn_mfma_f32_16x16x32_bf16(a0, bv, acc[0][nf], 0, 0, 0);
                acc[1][nf] = __builtin_amdgcn_mfma_f32_16x16x32_bf16(a1, bv, acc[1][nf], 0, 0, 0);
            }
        }
        __syncthreads();
    }
#undef GL_A
    // epilogue: pack to bf16 tile [128][136] in LDS, then fully-contiguous 16B stores
    const int wm = wave * 32;
#pragma unroll
    for (int mf = 0; mf < 2; ++mf) {
        const int row = wm + mf * 16 + 4 * (lane >> 4);
#pragma unroll
        for (int nf = 0; nf < 8; ++nf) {
            const int col = nf * 16 + (lane & 15);
#pragma unroll
            for (int r = 0; r < 4; ++r)
                Tt[(row + r) * 136 + col] = (short)f2bf(acc[mf][nf][r]);
        }
    }
    __syncthreads();
    const size_t gb = (size_t)mt * GMT + (size_t)nt * GNT;
    if (n0 < 8192) {
#pragma unroll
        for (int i = 0; i < 8; ++i) {
            const int idx = tid + i * 256;        // [0,2048)
            const int ml = idx >> 4, c8 = (idx & 15) * 8;
            const short8 v = *(const short8*)(&Tt[ml * 136 + c8]);
            *(short8*)(&fftG[gb + (size_t)idx * 8]) = v;
        }
    } else {
#pragma unroll
        for (int i = 0; i < 4; ++i) {
            const int idx = tid + i * 256;        // [0,1024)
            const int ml = idx >> 3, c8 = (idx & 7) * 8;
            const short8 v = *(const short8*)(&Tt[ml * 136 + c8]);
            *(short8*)(&fftG[gb + (size_t)idx * 8]) = v;
        }
    }
}

// ---------------- K5: S = sum_d fftU[b,d] * fftG[h,d]; y[b,h,:] = irfft(S)[0:4096] (bf16 out)
// Stage 1 fused into recombine; final stage fused into output (register butterflies). ----------------
extern "C" __global__ __launch_bounds__(512) void conv_ifft_k(
    const float2* __restrict__ fftU, const unsigned short* __restrict__ fftG,
    unsigned short* __restrict__ y) {
    __shared__ float2 A[LDSN];
    __shared__ float2 S4096;
    const int wg = blockIdx.x;  // 4096 blocks
    const int h = ((wg & 7) << 6) + (wg >> 6);  // XCD (wg&7) owns h range [x*64, x*64+64)
    const int b = (wg >> 3) & 7;
    const int tid = threadIdx.x;
    const float2* U = fftU + (size_t)b * MD * FS;
    const size_t mbase = (size_t)(h >> 5) * GMT + (size_t)((h & 31) * 4) * 128;
    const size_t tail = (size_t)(h >> 5) * GMT + (size_t)64 * GNT + (size_t)((h & 31) * 4) * 64;
#pragma unroll
    for (int j = 0; j < 9; ++j) {
        const int k = tid + j * 512;
        if (k <= 4096) {
            float2 s = make_float2(0.f, 0.f);
#pragma unroll
            for (int d = 0; d < MD; ++d) {
                const unsigned gv = (k < 4096)
                    ? *(const unsigned*)(fftG + mbase + (size_t)d * 128 + (size_t)(k >> 6) * GNT + (k & 63) * 2)
                    : *(const unsigned*)(fftG + tail + (size_t)d * 64);
                const float2 uu = U[d * FS + k];
                const float gx = __uint_as_float(gv << 16);
                const float gy = __uint_as_float(gv & 0xFFFF0000u);
                s.x = fmaf(uu.x, gx, fmaf(-uu.y, gy, s.x));
                s.y = fmaf(uu.x, gy, fmaf(uu.y, gx, s.y));
            }
            if (k < 4096) A[PD(k)] = s;
            else S4096 = s;
        }
    }
    __syncthreads();
    // recombine in registers (elements k = tid + 512j), then fused stage 1
    float2 c[8], bt[8];
#pragma unroll
    for (int j = 0; j < 8; ++j) {
        const int k = tid + j * 512;
        const float2 Sk = A[PD(k)];
        const float2 Sm = (k == 0) ? S4096 : A[PD(4096 - k)];
        const float2 E = make_float2(0.5f * (Sk.x + Sm.x), 0.5f * (Sk.y - Sm.y));
        const float2 D = make_float2(0.5f * (Sk.x - Sm.x), 0.5f * (Sk.y + Sm.y));
        const float2 t = g_tw8192[k];                    // exp(-i*2pi*k/8192)
        const float2 tc = make_float2(t.x, -t.y);        // need +angle here
        const float2 O = cmul(D, tc);
        c[j] = make_float2(E.x - O.y, E.y + O.x);
    }
    __syncthreads();   // all reads of A complete before stage-1 overwrite
    bfly8<1>(c, bt);
    A[PD(8 * tid + 0)] = bt[0];
#pragma unroll
    for (int j = 1; j < 8; ++j) {
        float2 t = g_tw4096[tid * j]; t.y = -t.y;        // conj for DIR=+1
        A[PD(8 * tid + j)] = cmul(bt[j], t);
    }
    __syncthreads();
    fft_stage_ip<1, 512, 8>(A, tid);
    fft_stage_ip<1, 64, 64>(A, tid);
    // fused final stage (p=0, twiddle-free): keep only positions < 2048
    {
        float2 z[8], bo[8];
#pragma unroll
        for (int k = 0; k < 8; ++k) z[k] = A[PD(tid + 512 * k)];
        bfly8<1>(z, bo);
        const float inv = 1.0f / 4096.0f;
#pragma unroll
        for (int k = 0; k < 4; ++k)   // same-thread same-address overwrite: no barrier needed
            A[PD(tid + 512 * k)] = make_float2(bo[k].x * inv, bo[k].y * inv);
    }
    __syncthreads();
    unsigned short* yp = y + (size_t)(b * HID + h) * LSEQ;
    {
        const int q = tid;  // 512 threads x 16B = full 8192-B row
        unsigned dw[4];
#pragma unroll
        for (int jj = 0; jj < 4; ++jj) {
            const float2 z = A[PD(4 * q + jj)];
            dw[jj] = (unsigned)f2bf(z.x) | ((unsigned)f2bf(z.y) << 16);
        }
        uint4 v; v.x = dw[0]; v.y = dw[1]; v.z = dw[2]; v.w = dw[3];
        *(uint4*)(yp + 8 * q) = v;
    }
}

// ---------------- K6: h = relu(x @ Whw_x^T + y^T + bias); 32m x 512h blocks so every
// wave store is a single contiguous 1024-B segment within one out row. ----------------
extern "C" __global__ __launch_bounds__(256) void out_gemm_k(
    const unsigned short* __restrict__ x_bf, const unsigned short* __restrict__ Wt,
    const float* __restrict__ Whb, const unsigned short* __restrict__ y,
    float* __restrict__ out) {
    __shared__ __align__(16) char smem[66560];
    short* As = (short*)smem;              // [32][40] shorts = 2560 B
    short* Bs = (short*)(smem + 2560);     // [512][40] shorts = 40960 B
    float* Whbs = (float*)smem;            // epilogue: 512 floats (aliases dead As)
    short* Ys = (short*)(smem + 2560);     // epilogue: bf16 [512][36] (aliases dead Bs)
    float* Ct = (float*)smem;              // epilogue: [32][520] floats = 66560 B

    const int tid = threadIdx.x, lane = tid & 63, wave = tid >> 6;
    // 1024 blocks = 8 XCDs * 128; XCD x owns batch b = x, t ascending
    const int wg = blockIdx.x;
    const int s = ((wg & 7) << 7) + (wg >> 3);
    const int m0 = s * 32;
    const int b = m0 >> 12;          // == wg & 7
    const int t0 = m0 & 4095;
    const int hq = wave * 128;       // wave's h-quarter

    floatx4 acc[2][8];
#pragma unroll
    for (int i = 0; i < 2; ++i)
#pragma unroll
        for (int j = 0; j < 8; ++j) acc[i][j] = (floatx4){0.f, 0.f, 0.f, 0.f};

    // staging: A (2 KB, threads<128), B = Wt chunk (32 KB contiguous, 128 B/thread)
    short8 ra, rb[8];
    const int arow = tid >> 2, acb = (tid & 3) * 8;
    if (tid < 128) ra = *(const short8*)(x_bf + (size_t)(m0 + arow) * INS + acb);
#pragma unroll
    for (int j = 0; j < 8; ++j)
        rb[j] = *(const short8*)(Wt + (size_t)tid * 64 + j * 8);

    for (int c = 0; c < 8; ++c) {
        if (tid < 128) *(short8*)(&As[arow * 40 + acb]) = ra;
#pragma unroll
        for (int j = 0; j < 8; ++j)
            *(short8*)(&Bs[(2 * tid + (j >> 2)) * 40 + (j & 3) * 8]) = rb[j];
        __syncthreads();
        if (c < 7) {
            if (tid < 128) ra = *(const short8*)(x_bf + (size_t)(m0 + arow) * INS + (c + 1) * 32 + acb);
#pragma unroll
            for (int j = 0; j < 8; ++j)
                rb[j] = *(const short8*)(Wt + (size_t)(c + 1) * 16384 + (size_t)tid * 64 + j * 8);
        }
        const int kq = 8 * (lane >> 4);
        const short8 a0 = *(const short8*)(&As[(lane & 15) * 40 + kq]);
        const short8 a1 = *(const short8*)(&As[((lane & 15) + 16) * 40 + kq]);
#pragma unroll
        for (int nf = 0; nf < 8; ++nf) {
            const short8 bv = *(const short8*)(&Bs[(hq + nf * 16 + (lane & 15)) * 40 + kq]);
            acc[0][nf] = __builtin_amdgcn_mfma_f32_16x16x32_bf16(a0, bv, acc[0][nf], 0, 0, 0);
            acc[1][nf] = __builtin_amdgcn_mfma_f32_16x16x32_bf16(a1, bv, acc[1][nf], 0, 0, 0);
        }
        __syncthreads();
    }

    // epilogue: stage bias + y^T (bf16), add+relu into acc, transpose via Ct, row stores
    Whbs[tid] = Whb[tid];
    Whbs[tid + 256] = Whb[tid + 256];
#pragma unroll
    for (int i = 0; i < 16; ++i) {
        const int idx = tid + i * 256;          // 0..4095
        const int hh = idx >> 3, tq = (idx & 7) * 4;
        const ush4 v = *(const ush4*)(y + (size_t)(b * HID + hh) * LSEQ + t0 + tq);
        *(ush4*)(&Ys[hh * 36 + tq]) = v;
    }
    __syncthreads();
#pragma unroll
    for (int nf = 0; nf < 8; ++nf) {
        const int hh = hq + nf * 16 + (lane & 15);
        const float bias = Whbs[hh];
#pragma unroll
        for (int mf = 0; mf < 2; ++mf)
#pragma unroll
            for (int r = 0; r < 4; ++r) {
                const int row = mf * 16 + 4 * (lane >> 4) + r;
                acc[mf][nf][r] = fmaxf(acc[mf][nf][r] + bf2f(Ys[hh * 36 + row]) + bias, 0.f);
            }
    }
    __syncthreads();   // all Ys/Whbs reads done before Ct overwrite
#pragma unroll
    for (int nf = 0; nf < 8; ++nf) {
        const int col = hq + nf * 16 + (lane & 15);
#pragma unroll
        for (int mf = 0; mf < 2; ++mf)
#pragma unroll
            for (int r = 0; r < 4; ++r) {
                const int row = mf * 16 + 4 * (lane >> 4) + r;
                Ct[row * 520 + col] = acc[mf][nf][r];
            }
    }
    __syncthreads();
#pragma unroll
    for (int i = 0; i < 16; ++i) {
        const int idx = tid + i * 256;          // 0..4095 float4s
        const int row = idx >> 7, c4 = (idx & 127) * 4;
        const floatx4 t = *(const floatx4*)&Ct[row * 520 + c4];
        *(floatx4*)(out + (size_t)(m0 + row) * HID + c4) = t;
        if (((m0 + row) & 4095) == 4095)
            *(floatx4*)(out + (size_t)NB * LSEQ * HID + (size_t)b * HID + c4) = t;
    }
}

extern "C" void kernel_launch(void* const* d_in, const int* in_sizes, int n_in,
                              void* d_out, int out_size, void* d_ws, size_t ws_size,
                              hipStream_t stream) {
    const float* x   = (const float*)d_in[0];
    const float* Wuw = (const float*)d_in[1];
    const float* Wub = (const float*)d_in[2];
    const float* Whw = (const float*)d_in[3];
    const float* Whb = (const float*)d_in[4];
    const float* H   = (const float*)d_in[5];
    char* wsb = (char*)d_ws;
    // workspace layout — byte-identical footprint to the verified round-1 layout
    unsigned short* fftG   = (unsigned short*)(wsb);             // blocked, 33,816,576 B
    unsigned short* yb     = (unsigned short*)(wsb + 33816576);  // 8*512*4096 bf16  = 33,554,432
    float*          fftU   = (float*)(wsb + 67371008);           // 32*4128*2 fp32   =  1,056,768
    unsigned short* fftHT  = (unsigned short*)(wsb + 68427776);  // 8256*256 bf16    =  4,227,072
    float*          ut     = (float*)(wsb + 72654848);           // 32*4096 fp32     =    524,288
    unsigned short* x_bf   = (unsigned short*)(wsb + 73179136);  // 32768*256 bf16   = 16,777,216
    unsigned short* Whw_bf = (unsigned short*)(wsb + 89956352);  // [512][1024] bf16 =  1,048,576
    unsigned short* Wt     = (unsigned short*)(wsb + 91004928);  // [8][512][32] bf16=    262,144
    unsigned short* fftHB  = (unsigned short*)(wsb + 91267072);  // 256*8256 bf16    =  4,227,072
    float* out = (float*)d_out;

    hipLaunchKernelGGL(u_relu_k, dim3(8865), dim3(256), 0, stream, x, Wuw, Wub, ut, x_bf, Whw, Whw_bf, Wt);
    hipLaunchKernelGGL(rfft_all_k, dim3(288), dim3(512), 0, stream, ut, H, (float2*)fftU, fftHB);
    hipLaunchKernelGGL(ht2_k, dim3(129, 4), dim3(256), 0, stream, fftHB, fftHT);
    hipLaunchKernelGGL(g_gemm_k, dim3(1040), dim3(256), 0, stream, Whw_bf, fftHT, fftG);
    hipLaunchKernelGGL(conv_ifft_k, dim3(4096), dim3(512), 0, stream,
                       (const float2*)fftU, fftG, yb);
    hipLaunchKernelGGL(out_gemm_k, dim3(1024), dim3(256), 0, stream, x_bf, Wt, Whb, yb, out);
}